// Round 13
// baseline (706.464 us; speedup 1.0000x reference)
//
#include <hip/hip_runtime.h>
#include <hip/hip_bf16.h>
#include <math.h>

#define H 300
#define WAVE 64
#define STRB 320   // padded bf16 row stride (640 B; 40 chunks of 16 B)
#define SCB 1024

typedef short bf16x8 __attribute__((ext_vector_type(8)));
typedef unsigned short u16;
typedef u16 u16x8 __attribute__((ext_vector_type(8)));
typedef float f32x4 __attribute__((ext_vector_type(4)));

__device__ inline unsigned short f2b(float f) {
    union { float f; unsigned int u; } x; x.f = f;
    unsigned int r = x.u + 0x7FFF + ((x.u >> 16) & 1);
    return (unsigned short)(r >> 16);
}
__device__ inline float b2f(u16 h) {
    union { float f; unsigned int u; } x; x.u = ((unsigned int)h) << 16;
    return x.f;
}

// ---------------------------------------------------------------------------
// l2 normalize rows: one wave per row; bf16 padded output only
// ---------------------------------------------------------------------------
__global__ void k_l2norm(const float* __restrict__ x, u16* __restrict__ outb, int n) {
    int wave = blockIdx.x * (blockDim.x / WAVE) + (threadIdx.x >> 6);
    int lane = threadIdx.x & 63;
    if (wave >= n) return;
    const float* row = x + (long)wave * H;
    float s = 0.f;
    for (int j = lane; j < H; j += WAVE) { float v = row[j]; s += v * v; }
    for (int o = 32; o > 0; o >>= 1) s += __shfl_xor(s, o);
    float sc = 1.0f / fmaxf(sqrtf(s), 1e-12f);
    u16* brow = outb + (long)wave * STRB;
    for (int j = lane; j < H; j += WAVE) brow[j] = f2b(row[j] * sc);
    for (int j = H + lane; j < STRB; j += WAVE) brow[j] = 0;
}

__global__ void k_zero_int(int* p, int n) {
    int i = blockIdx.x * blockDim.x + threadIdx.x;
    int stride = gridDim.x * blockDim.x;
    for (; i < n; i += stride) p[i] = 0;
}

__global__ void k_count_deg(const int* __restrict__ ei_i, int* __restrict__ deg, int E) {
    int i = blockIdx.x * blockDim.x + threadIdx.x;
    int stride = gridDim.x * blockDim.x;
    for (; i < E; i += stride) atomicAdd(&deg[ei_i[i]], 1);
}

// ---------------------------------------------------------------------------
// parallel exclusive scan of deg -> offs(+cursor), offs[n]=total; dinv fused
// ---------------------------------------------------------------------------
__global__ void k_scan_local(const int* __restrict__ deg, int* __restrict__ offs,
                             int* __restrict__ btot, float* __restrict__ dinv, int n) {
    __shared__ int sh[SCB];
    int base = blockIdx.x * SCB;
    int tid = threadIdx.x;
    int v = (base + tid < n) ? deg[base + tid] : 0;
    if (base + tid < n) dinv[base + tid] = (v > 0) ? 1.0f / sqrtf((float)v) : 0.0f;
    sh[tid] = v;
    __syncthreads();
    for (int off = 1; off < SCB; off <<= 1) {
        int add = (tid >= off) ? sh[tid - off] : 0;
        __syncthreads();
        sh[tid] += add;
        __syncthreads();
    }
    if (base + tid < n) offs[base + tid] = sh[tid] - v;
    if (tid == SCB - 1) btot[blockIdx.x] = sh[tid];
}

__global__ void k_scan_tots(const int* __restrict__ btot, int* __restrict__ bpre,
                            int nb, int* __restrict__ total_out) {
    int l = threadIdx.x;   // single wave of 64; nb <= 64
    int v = (l < nb) ? btot[l] : 0;
    int own = v;
    for (int o = 1; o < 64; o <<= 1) {
        int u = __shfl_up(v, o);
        if (l >= o) v += u;
    }
    if (l < nb) bpre[l] = v - own;
    if (l == 63) total_out[0] = v;
}

__global__ void k_scan_apply(int* __restrict__ offs, const int* __restrict__ bpre,
                             int* __restrict__ cursor, int n) {
    int i = blockIdx.x * blockDim.x + threadIdx.x;
    int stride = gridDim.x * blockDim.x;
    for (; i < n; i += stride) {
        int o = offs[i] + bpre[i / SCB];
        offs[i] = o;
        cursor[i] = o;
    }
}

__global__ void k_fill_csr(const int* __restrict__ ei_j, const int* __restrict__ ei_i,
                           int* __restrict__ cursor, int* __restrict__ csr_src, int E) {
    int i = blockIdx.x * blockDim.x + threadIdx.x;
    int stride = gridDim.x * blockDim.x;
    for (; i < E; i += stride) {
        int dst = ei_i[i];
        int pos = atomicAdd(&cursor[dst], 1);
        csr_src[pos] = ei_j[i];
    }
}

// ---------------------------------------------------------------------------
// 4x W fp32 [300][300] -> padded bf16 [320][320], pads zero. One launch.
// ---------------------------------------------------------------------------
__global__ void k_conv_w4(const float* __restrict__ W0f, const float* __restrict__ W1f,
                          const float* __restrict__ W2f, const float* __restrict__ W3f,
                          u16* __restrict__ Wb0, u16* __restrict__ Wb1,
                          u16* __restrict__ Wb2, u16* __restrict__ Wb3) {
    int which = blockIdx.x & 3;
    const float* W = (which == 0) ? W0f : (which == 1) ? W1f : (which == 2) ? W2f : W3f;
    u16* Wb = (which == 0) ? Wb0 : (which == 1) ? Wb1 : (which == 2) ? Wb2 : Wb3;
    int idx = (blockIdx.x >> 2) * blockDim.x + threadIdx.x;
    int stride = (gridDim.x >> 2) * blockDim.x;
    for (; idx < STRB * STRB; idx += stride) {
        int r = idx / STRB, c = idx - r * STRB;
        Wb[idx] = (r < H && c < H) ? f2b(W[r * H + c]) : 0;
    }
}

// ---------------------------------------------------------------------------
// MFMA NT GEMM, BM=128 x BN=64, 1-D grid bn-fast + bijective XCD swizzle.
// Epilogue via LDS re-tile, fully vectorized; optional fused dual-dot
// (atomicAdd partials into sbi/sbj, which must be zeroed beforehand).
// ---------------------------------------------------------------------------
#define BM 128
#define BN 64
#define BK 32
#define LDP 40
#define STP 70   // epilogue staging stride (u16)
#define NXCD 8

__global__ __launch_bounds__(256) void k_gemm_fused(
        const u16* __restrict__ Xb,
        const u16* __restrict__ Wb,
        u16* __restrict__ outb,
        const float* __restrict__ hwbias,
        const u16* __restrict__ xnewb, const float* __restrict__ xnewf,
        const u16* __restrict__ xold,
        float* __restrict__ outf, long ostride,
        u16* __restrict__ mirror,
        const float* __restrict__ dai, const float* __restrict__ daj,
        float* __restrict__ sbi, float* __restrict__ sbj,
        int n_rows) {
    __shared__ __align__(16) char smem[BM * STP * 2];   // 17920 B
    short* As = (short*)smem;                           // [BM][LDP]
    short* Bs = (short*)(smem + BM * LDP * 2);          // [BN][LDP]
    u16*   St = (u16*)smem;                             // [BM][STP] (epilogue)
    const int tid = threadIdx.x;

    const int nwg = gridDim.x;
    const int q = nwg / NXCD, r = nwg % NXCD;
    const int xcd = blockIdx.x % NXCD, idx = blockIdx.x / NXCD;
    const int wgid = (xcd < r ? xcd * (q + 1) : r * (q + 1) + (xcd - r) * q) + idx;
    const int bm = (wgid / 5) * BM;
    const int bn = (wgid % 5) * BN;

    const int lane = tid & 63;
    const int wid = tid >> 6;
    const int wr = wid >> 1;
    const int wc = wid & 1;
    const int lrow = lane & 15;
    const int kgrp = lane >> 4;

    f32x4 acc[4][2];
    #pragma unroll
    for (int m = 0; m < 4; m++)
        #pragma unroll
        for (int n = 0; n < 2; n++) acc[m][n] = (f32x4){0.f, 0.f, 0.f, 0.f};

    for (int k0 = 0; k0 < STRB; k0 += BK) {
        #pragma unroll
        for (int i = 0; i < 2; ++i) {
            int qq = tid + i * 256;
            int rr = qq >> 2, c = (qq & 3) << 3;
            int gr = bm + rr;
            u16x8 v = {0, 0, 0, 0, 0, 0, 0, 0};
            if (gr < n_rows) v = *(const u16x8*)&Xb[(long)gr * STRB + k0 + c];
            *(u16x8*)&As[rr * LDP + c] = v;
        }
        {
            int rr = tid >> 2, c = (tid & 3) << 3;
            u16x8 v = *(const u16x8*)&Wb[(long)(bn + rr) * STRB + k0 + c];
            *(u16x8*)&Bs[rr * LDP + c] = v;
        }
        __syncthreads();

        bf16x8 af[4], bfr[2];
        #pragma unroll
        for (int m = 0; m < 4; m++) {
            int row = wr * 64 + m * 16 + lrow;
            af[m] = *(const bf16x8*)&As[row * LDP + kgrp * 8];
        }
        #pragma unroll
        for (int n = 0; n < 2; n++) {
            int col = wc * 32 + n * 16 + lrow;
            bfr[n] = *(const bf16x8*)&Bs[col * LDP + kgrp * 8];
        }
        #pragma unroll
        for (int m = 0; m < 4; m++)
            #pragma unroll
            for (int n = 0; n < 2; n++)
                acc[m][n] = __builtin_amdgcn_mfma_f32_16x16x32_bf16(af[m], bfr[n], acc[m][n], 0, 0, 0);
        __syncthreads();
    }

    // stage acc (bf16) into LDS tile [128][STP]
    #pragma unroll
    for (int m = 0; m < 4; m++)
        #pragma unroll
        for (int n = 0; n < 2; n++) {
            int lc = wc * 32 + n * 16 + lrow;
            #pragma unroll
            for (int rr = 0; rr < 4; rr++) {
                int row = wr * 64 + m * 16 + kgrp * 4 + rr;
                St[row * STP + lc] = f2b(acc[m][n][rr]);
            }
        }
    __syncthreads();

    // vectorized epilogue: 8 threads/row, 4 passes of 32 rows
    #pragma unroll
    for (int p = 0; p < 4; p++) {
        int row = p * 32 + (tid >> 3);
        int gr = bm + row;
        if (gr >= n_rows) continue;
        int lc0 = (tid & 7) * 8;
        int gc0 = bn + lc0;
        u16x8 pv = *(const u16x8*)&St[row * STP + lc0];
        if (outb) {
            u16x8 o;
            #pragma unroll
            for (int j = 0; j < 8; j++) o[j] = (gc0 + j < H) ? pv[j] : (u16)0;
            *(u16x8*)&outb[(long)gr * STRB + gc0] = o;
        } else {
            u16x8 xov = *(const u16x8*)&xold[(long)gr * STRB + gc0];
            float xn[8];
            if (xnewb) {
                u16x8 xnv = *(const u16x8*)&xnewb[(long)gr * STRB + gc0];
                #pragma unroll
                for (int j = 0; j < 8; j++) xn[j] = b2f(xnv[j]);
            } else {
                f32x4 a = *(const f32x4*)&xnewf[(long)gr * H + gc0];
                f32x4 b = *(const f32x4*)&xnewf[(long)gr * H + gc0 + 4];
                xn[0] = a[0]; xn[1] = a[1]; xn[2] = a[2]; xn[3] = a[3];
                xn[4] = b[0]; xn[5] = b[1]; xn[6] = b[2]; xn[7] = b[3];
            }
            float val[8];
            #pragma unroll
            for (int j = 0; j < 8; j++) {
                int gcj = gc0 + j;
                if (gcj < H) {
                    float pre = b2f(pv[j]) + hwbias[gcj];
                    float g = 1.0f / (1.0f + __expf(-pre));
                    val[j] = g * xn[j] + (1.0f - g) * b2f(xov[j]);
                } else val[j] = 0.f;
            }
            if (outf) {
                if (gc0 < H)
                    *(f32x4*)&outf[(long)gr * ostride + gc0] = (f32x4){val[0], val[1], val[2], val[3]};
                if (gc0 + 4 < H)
                    *(f32x4*)&outf[(long)gr * ostride + gc0 + 4] = (f32x4){val[4], val[5], val[6], val[7]};
            }
            if (mirror) {
                u16x8 mv;
                #pragma unroll
                for (int j = 0; j < 8; j++) mv[j] = f2b(val[j]);
                *(u16x8*)&mirror[(long)gr * STRB + gc0] = mv;
            }
            if (dai) {
                float p0 = 0.f, p1 = 0.f;
                #pragma unroll
                for (int j = 0; j < 8; j++) {
                    int gcj = gc0 + j;
                    if (gcj < H) {
                        p0 += val[j] * dai[gcj];
                        p1 += val[j] * daj[gcj];
                    }
                }
                // reduce across the 8 threads of this row (contiguous lanes)
                #pragma unroll
                for (int o = 4; o > 0; o >>= 1) {
                    p0 += __shfl_down(p0, o);
                    p1 += __shfl_down(p1, o);
                }
                if ((tid & 7) == 0) {
                    atomicAdd(&sbi[gr], p0);
                    atomicAdd(&sbj[gr], p1);
                }
            }
        }
    }
}

// ---------------------------------------------------------------------------
// GCN gather, wave-per-node, unroll-4 edge pipeline. No LDS, no barriers.
// ---------------------------------------------------------------------------
__global__ __launch_bounds__(256) void k_gcn_gather_w(const u16* __restrict__ xb,
                                                      const float* __restrict__ dinv,
                                                      const int* __restrict__ offs,
                                                      const int* __restrict__ csr,
                                                      u16* __restrict__ outb, int n) {
    int node = blockIdx.x * 4 + (threadIdx.x >> 6);
    int lane = threadIdx.x & 63;
    if (node >= n) return;
    int start = offs[node], end = offs[node + 1];
    float acc[8];
    #pragma unroll
    for (int j = 0; j < 8; j++) acc[j] = 0.f;
    float di = dinv[node];
    const u16* rowp = xb + lane * 8;
    for (int tb = start; tb < end; tb += 64) {
        int p = tb + lane;
        int src = 0; float w = 0.f;
        if (p < end) {
            src = csr[p];
            w = di * dinv[src];
        }
        int cnt = min(64, end - tb);
        int qq = 0;
        for (; qq + 4 <= cnt; qq += 4) {
            float w0 = __shfl(w, qq), w1 = __shfl(w, qq + 1);
            float w2 = __shfl(w, qq + 2), w3 = __shfl(w, qq + 3);
            int s0 = __shfl(src, qq), s1 = __shfl(src, qq + 1);
            int s2 = __shfl(src, qq + 2), s3 = __shfl(src, qq + 3);
            if (lane < 40) {
                u16x8 v0 = *(const u16x8*)&rowp[(long)s0 * STRB];
                u16x8 v1 = *(const u16x8*)&rowp[(long)s1 * STRB];
                u16x8 v2 = *(const u16x8*)&rowp[(long)s2 * STRB];
                u16x8 v3 = *(const u16x8*)&rowp[(long)s3 * STRB];
                #pragma unroll
                for (int j = 0; j < 8; j++) acc[j] += w0 * b2f(v0[j]);
                #pragma unroll
                for (int j = 0; j < 8; j++) acc[j] += w1 * b2f(v1[j]);
                #pragma unroll
                for (int j = 0; j < 8; j++) acc[j] += w2 * b2f(v2[j]);
                #pragma unroll
                for (int j = 0; j < 8; j++) acc[j] += w3 * b2f(v3[j]);
            }
        }
        for (; qq < cnt; qq++) {
            float wq = __shfl(w, qq);
            int sq = __shfl(src, qq);
            if (lane < 40) {
                u16x8 v = *(const u16x8*)&rowp[(long)sq * STRB];
                #pragma unroll
                for (int j = 0; j < 8; j++) acc[j] += wq * b2f(v[j]);
            }
        }
    }
    if (lane < 40) {
        u16x8 o;
        #pragma unroll
        for (int j = 0; j < 8; j++) o[j] = f2b(fmaxf(acc[j], 0.f));
        *(u16x8*)&outb[(long)node * STRB + lane * 8] = o;
    }
}

// ---------------------------------------------------------------------------
// GAT gather, wave-per-node, fused softmax + unroll-4 edge pipeline.
// ---------------------------------------------------------------------------
__global__ __launch_bounds__(256) void k_gat_gather_w(const u16* __restrict__ xb,
                                                      const float* __restrict__ s_i_arr,
                                                      const float* __restrict__ s_j_arr,
                                                      const int* __restrict__ offs,
                                                      const int* __restrict__ csr,
                                                      u16* __restrict__ outb16,
                                                      float* __restrict__ outf, long out_stride,
                                                      int out_off, int n) {
    int node = blockIdx.x * 4 + (threadIdx.x >> 6);
    int lane = threadIdx.x & 63;
    if (node >= n) return;
    int start = offs[node], end = offs[node + 1];
    int deg = end - start;
    float acc[8];
    #pragma unroll
    for (int j = 0; j < 8; j++) acc[j] = 0.f;

    if (deg > 0) {
        float si = s_i_arr[node];
        float m_t = -1e30f, s_t = 0.f;
        for (int p = start + lane; p < end; p += 64) {
            float sc = si + s_j_arr[csr[p]];
            sc = (sc >= 0.f) ? sc : 0.01f * sc;
            if (sc > m_t) { s_t = s_t * __expf(m_t - sc) + 1.0f; m_t = sc; }
            else s_t += __expf(sc - m_t);
        }
        for (int o = 32; o > 0; o >>= 1) {
            float m2 = __shfl_xor(m_t, o), s2 = __shfl_xor(s_t, o);
            float mm = fmaxf(m_t, m2);
            s_t = s_t * __expf(m_t - mm) + s2 * __expf(m2 - mm);
            m_t = mm;
        }
        float m = m_t;
        float inv = 1.0f / (s_t + 1e-16f);
        const u16* rowp = xb + lane * 8;
        for (int tb = start; tb < end; tb += 64) {
            int p = tb + lane;
            int src = 0; float w = 0.f;
            if (p < end) {
                src = csr[p];
                float sc = si + s_j_arr[src];
                sc = (sc >= 0.f) ? sc : 0.01f * sc;
                w = __expf(sc - m) * inv;
            }
            int cnt = min(64, end - tb);
            int qq = 0;
            for (; qq + 4 <= cnt; qq += 4) {
                float w0 = __shfl(w, qq), w1 = __shfl(w, qq + 1);
                float w2 = __shfl(w, qq + 2), w3 = __shfl(w, qq + 3);
                int s0 = __shfl(src, qq), s1 = __shfl(src, qq + 1);
                int s2 = __shfl(src, qq + 2), s3 = __shfl(src, qq + 3);
                if (lane < 40) {
                    u16x8 v0 = *(const u16x8*)&rowp[(long)s0 * STRB];
                    u16x8 v1 = *(const u16x8*)&rowp[(long)s1 * STRB];
                    u16x8 v2 = *(const u16x8*)&rowp[(long)s2 * STRB];
                    u16x8 v3 = *(const u16x8*)&rowp[(long)s3 * STRB];
                    #pragma unroll
                    for (int j = 0; j < 8; j++) acc[j] += w0 * b2f(v0[j]);
                    #pragma unroll
                    for (int j = 0; j < 8; j++) acc[j] += w1 * b2f(v1[j]);
                    #pragma unroll
                    for (int j = 0; j < 8; j++) acc[j] += w2 * b2f(v2[j]);
                    #pragma unroll
                    for (int j = 0; j < 8; j++) acc[j] += w3 * b2f(v3[j]);
                }
            }
            for (; qq < cnt; qq++) {
                float wq = __shfl(w, qq);
                int sq = __shfl(src, qq);
                if (lane < 40) {
                    u16x8 v = *(const u16x8*)&rowp[(long)sq * STRB];
                    #pragma unroll
                    for (int j = 0; j < 8; j++) acc[j] += wq * b2f(v[j]);
                }
            }
        }
    }
    if (outb16) {
        if (lane < 40) {
            u16x8 o;
            #pragma unroll
            for (int j = 0; j < 8; j++) o[j] = f2b(fmaxf(acc[j], 0.f));
            *(u16x8*)&outb16[(long)node * STRB + lane * 8] = o;
        }
    } else {
        if (lane < 38) {
            #pragma unroll
            for (int j = 0; j < 8; j++) {
                int c = lane * 8 + j;
                if (c < H) outf[(long)node * out_stride + out_off + c] = fmaxf(acc[j], 0.f);
            }
        }
    }
}

// ---------------------------------------------------------------------------
// launch
// ---------------------------------------------------------------------------
extern "C" void kernel_launch(void* const* d_in, const int* in_sizes, int n_in,
                              void* d_out, int out_size, void* d_ws, size_t ws_size,
                              hipStream_t stream) {
    const float* x_e     = (const float*)d_in[0];
    const int*   ei_all  = (const int*)d_in[3];
    const float* gcn1_W  = (const float*)d_in[5];
    const float* hw1_W   = (const float*)d_in[6];
    const float* hw1_b   = (const float*)d_in[7];
    const float* gat1_ai = (const float*)d_in[8];
    const float* gat1_aj = (const float*)d_in[9];
    const float* ghw1_W  = (const float*)d_in[10];
    const float* ghw1_b  = (const float*)d_in[11];
    const float* gat2_ai = (const float*)d_in[12];
    const float* gat2_aj = (const float*)d_in[13];
    const float* ghw2_W  = (const float*)d_in[14];
    const float* ghw2_b  = (const float*)d_in[15];
    const float* gat_ai  = (const float*)d_in[16];
    const float* gat_aj  = (const float*)d_in[17];

    const int N = in_sizes[0] / H;
    const int E = in_sizes[3] / 2;
    const int* ei_j = ei_all;
    const int* ei_i = ei_all + E;

    float* out = (float*)d_out;

    size_t NSB = (size_t)N * STRB;
    u16*   W0   = (u16*)d_ws;
    u16*   W1   = W0 + NSB;
    u16*   W2   = W1 + NSB;
    u16*   W3   = W2 + NSB;
    float* G2F  = (float*)d_ws;              // spans [0, 60MB) ⊂ W0+W1 (64MB)
    float* sbi  = (float*)(W3 + NSB);
    float* sbj  = sbi + N;
    float* dinv = sbj + N;
    int*   deg  = (int*)(dinv + N);
    int*   offs = deg + N;                   // N+1
    int*   cursor = offs + (N + 1);
    int*   csr  = cursor + N;                // E ints
    int*   btot = csr + E;                   // 64
    int*   bpre = btot + 64;                 // 64
    u16*   wb0  = (u16*)(bpre + 64);         // 4 x 320x320 bf16 weights
    u16*   wb1  = wb0 + STRB * STRB;
    u16*   wb2  = wb1 + STRB * STRB;
    u16*   wb3  = wb2 + STRB * STRB;

    dim3 blk256(256);
    int rowsPerBlock = 256 / WAVE;
    dim3 gridRows((N + rowsPerBlock - 1) / rowsPerBlock);
    dim3 gridNodeW((N + 3) / 4);
    dim3 gridE(2048);
    dim3 gridW(400);
    dim3 gridGemm(((N + BM - 1) / BM) * 5);
    int nScanB = (N + SCB - 1) / SCB;

    // 1. x0b = bf16(l2_normalize(x_e)) -> W0
    hipLaunchKernelGGL(k_l2norm, gridRows, blk256, 0, stream, x_e, W0, N);

    // 2. CSR build + weight conversion
    hipLaunchKernelGGL(k_zero_int, dim3(256), blk256, 0, stream, deg, N);
    hipLaunchKernelGGL(k_count_deg, gridE, blk256, 0, stream, ei_i, deg, E);
    hipLaunchKernelGGL(k_scan_local, dim3(nScanB), dim3(SCB), 0, stream, deg, offs, btot, dinv, N);
    hipLaunchKernelGGL(k_scan_tots, dim3(1), dim3(64), 0, stream, btot, bpre, nScanB, offs + N);
    hipLaunchKernelGGL(k_scan_apply, dim3(256), blk256, 0, stream, offs, bpre, cursor, N);
    hipLaunchKernelGGL(k_fill_csr, gridE, blk256, 0, stream, ei_j, ei_i, cursor, csr, E);
    hipLaunchKernelGGL(k_conv_w4, gridW, blk256, 0, stream,
                       gcn1_W, hw1_W, ghw1_W, ghw2_W, wb0, wb1, wb2, wb3);

    // 3. hb = bf16(x0 @ gcn1_W.T) -> W1
    hipLaunchKernelGGL(k_gemm_fused, gridGemm, blk256, 0, stream,
                       W0, wb0, W1,
                       (const float*)nullptr, (const u16*)nullptr, (const float*)nullptr,
                       (const u16*)nullptr, (float*)nullptr, (long)0, (u16*)nullptr,
                       (const float*)nullptr, (const float*)nullptr,
                       (float*)nullptr, (float*)nullptr, N);

    // 4. gcnb -> W2
    hipLaunchKernelGGL(k_gcn_gather_w, gridNodeW, blk256, 0, stream, W1, dinv, offs, csr, W2, N);

    // 5. x2b = hw(x0b, gcnb) fused + gat1 dots: pre = x0b@hw1_W.T -> mirror W3
    hipMemsetAsync(sbi, 0, 2 * (size_t)N * sizeof(float), stream);
    hipLaunchKernelGGL(k_gemm_fused, gridGemm, blk256, 0, stream,
                       W0, wb1, (u16*)nullptr,
                       hw1_b, W2, (const float*)nullptr, W0,
                       (float*)nullptr, (long)0, W3,
                       gat1_ai, gat1_aj, sbi, sbj, N);

    // 7. GAT1 gather on x2b -> g1b (W1)
    hipLaunchKernelGGL(k_gat_gather_w, gridNodeW, blk256, 0, stream, W3, sbi, sbj, offs, csr,
                       W1, (float*)nullptr, (long)0, 0, N);

    // 8. x3b = hw(x2b, g1b) fused + gat2 dots: pre = x2b@ghw1_W.T -> mirror W2
    hipMemsetAsync(sbi, 0, 2 * (size_t)N * sizeof(float), stream);
    hipLaunchKernelGGL(k_gemm_fused, gridGemm, blk256, 0, stream,
                       W3, wb2, (u16*)nullptr,
                       ghw1_b, W1, (const float*)nullptr, W3,
                       (float*)nullptr, (long)0, W2,
                       gat2_ai, gat2_aj, sbi, sbj, N);

    // 10. GAT2 gather on x3b -> G2F (fp32, contiguous stride H)
    hipLaunchKernelGGL(k_gat_gather_w, gridNodeW, blk256, 0, stream, W2, sbi, sbj, offs, csr,
                       (u16*)nullptr, G2F, (long)H, 0, N);

    // 11. xe = hw(x2b, G2F) fused + final dots: pre = x2b@ghw2_W.T
    //     -> d_out[:,0:300] fp32 + mirror xeb (W2)
    hipMemsetAsync(sbi, 0, 2 * (size_t)N * sizeof(float), stream);
    hipLaunchKernelGGL(k_gemm_fused, gridGemm, blk256, 0, stream,
                       W3, wb3, (u16*)nullptr,
                       ghw2_b, (const u16*)nullptr, G2F, W3,
                       out, (long)(2 * H), W2,
                       gat_ai, gat_aj, sbi, sbj, N);

    // 13. final GAT gather on xeb -> d_out[:,300:600]
    hipLaunchKernelGGL(k_gat_gather_w, gridNodeW, blk256, 0, stream, W2, sbi, sbj, offs, csr,
                       (u16*)nullptr, out, (long)(2 * H), H, N);
}

// Round 14
// 683.233 us; speedup vs baseline: 1.0340x; 1.0340x over previous
//
#include <hip/hip_runtime.h>
#include <hip/hip_bf16.h>
#include <math.h>

#define H 300
#define WAVE 64
#define STRB 320   // padded bf16 row stride (640 B; 40 chunks of 16 B)
#define SCB 1024

typedef short bf16x8 __attribute__((ext_vector_type(8)));
typedef unsigned short u16;
typedef u16 u16x8 __attribute__((ext_vector_type(8)));
typedef u16 u16x4 __attribute__((ext_vector_type(4)));
typedef float f32x4 __attribute__((ext_vector_type(4)));

__device__ inline unsigned short f2b(float f) {
    union { float f; unsigned int u; } x; x.f = f;
    unsigned int r = x.u + 0x7FFF + ((x.u >> 16) & 1);
    return (unsigned short)(r >> 16);
}
__device__ inline float b2f(u16 h) {
    union { float f; unsigned int u; } x; x.u = ((unsigned int)h) << 16;
    return x.f;
}

// ---------------------------------------------------------------------------
// l2 normalize rows: one wave per row; bf16 padded output only
// ---------------------------------------------------------------------------
__global__ void k_l2norm(const float* __restrict__ x, u16* __restrict__ outb, int n) {
    int wave = blockIdx.x * (blockDim.x / WAVE) + (threadIdx.x >> 6);
    int lane = threadIdx.x & 63;
    if (wave >= n) return;
    const float* row = x + (long)wave * H;
    float s = 0.f;
    for (int j = lane; j < H; j += WAVE) { float v = row[j]; s += v * v; }
    for (int o = 32; o > 0; o >>= 1) s += __shfl_xor(s, o);
    float sc = 1.0f / fmaxf(sqrtf(s), 1e-12f);
    u16* brow = outb + (long)wave * STRB;
    for (int j = lane; j < H; j += WAVE) brow[j] = f2b(row[j] * sc);
    for (int j = H + lane; j < STRB; j += WAVE) brow[j] = 0;
}

__global__ void k_zero_int(int* p, int n) {
    int i = blockIdx.x * blockDim.x + threadIdx.x;
    int stride = gridDim.x * blockDim.x;
    for (; i < n; i += stride) p[i] = 0;
}

__global__ void k_count_deg(const int* __restrict__ ei_i, int* __restrict__ deg, int E) {
    int i = blockIdx.x * blockDim.x + threadIdx.x;
    int stride = gridDim.x * blockDim.x;
    for (; i < E; i += stride) atomicAdd(&deg[ei_i[i]], 1);
}

// ---------------------------------------------------------------------------
// parallel exclusive scan of deg -> offs(+cursor), offs[n]=total; dinv fused
// ---------------------------------------------------------------------------
__global__ void k_scan_local(const int* __restrict__ deg, int* __restrict__ offs,
                             int* __restrict__ btot, float* __restrict__ dinv, int n) {
    __shared__ int sh[SCB];
    int base = blockIdx.x * SCB;
    int tid = threadIdx.x;
    int v = (base + tid < n) ? deg[base + tid] : 0;
    if (base + tid < n) dinv[base + tid] = (v > 0) ? 1.0f / sqrtf((float)v) : 0.0f;
    sh[tid] = v;
    __syncthreads();
    for (int off = 1; off < SCB; off <<= 1) {
        int add = (tid >= off) ? sh[tid - off] : 0;
        __syncthreads();
        sh[tid] += add;
        __syncthreads();
    }
    if (base + tid < n) offs[base + tid] = sh[tid] - v;
    if (tid == SCB - 1) btot[blockIdx.x] = sh[tid];
}

__global__ void k_scan_tots(const int* __restrict__ btot, int* __restrict__ bpre,
                            int nb, int* __restrict__ total_out) {
    int l = threadIdx.x;   // single wave of 64; nb <= 64
    int v = (l < nb) ? btot[l] : 0;
    int own = v;
    for (int o = 1; o < 64; o <<= 1) {
        int u = __shfl_up(v, o);
        if (l >= o) v += u;
    }
    if (l < nb) bpre[l] = v - own;
    if (l == 63) total_out[0] = v;
}

__global__ void k_scan_apply(int* __restrict__ offs, const int* __restrict__ bpre,
                             int* __restrict__ cursor, int n) {
    int i = blockIdx.x * blockDim.x + threadIdx.x;
    int stride = gridDim.x * blockDim.x;
    for (; i < n; i += stride) {
        int o = offs[i] + bpre[i / SCB];
        offs[i] = o;
        cursor[i] = o;
    }
}

__global__ void k_fill_csr(const int* __restrict__ ei_j, const int* __restrict__ ei_i,
                           int* __restrict__ cursor, int* __restrict__ csr_src, int E) {
    int i = blockIdx.x * blockDim.x + threadIdx.x;
    int stride = gridDim.x * blockDim.x;
    for (; i < E; i += stride) {
        int dst = ei_i[i];
        int pos = atomicAdd(&cursor[dst], 1);
        csr_src[pos] = ei_j[i];
    }
}

// ---------------------------------------------------------------------------
// 4x W fp32 [300][300] -> padded bf16 [320][320], pads zero. One launch.
// ---------------------------------------------------------------------------
__global__ void k_conv_w4(const float* __restrict__ W0f, const float* __restrict__ W1f,
                          const float* __restrict__ W2f, const float* __restrict__ W3f,
                          u16* __restrict__ Wb0, u16* __restrict__ Wb1,
                          u16* __restrict__ Wb2, u16* __restrict__ Wb3) {
    int which = blockIdx.x & 3;
    const float* W = (which == 0) ? W0f : (which == 1) ? W1f : (which == 2) ? W2f : W3f;
    u16* Wb = (which == 0) ? Wb0 : (which == 1) ? Wb1 : (which == 2) ? Wb2 : Wb3;
    int idx = (blockIdx.x >> 2) * blockDim.x + threadIdx.x;
    int stride = (gridDim.x >> 2) * blockDim.x;
    for (; idx < STRB * STRB; idx += stride) {
        int r = idx / STRB, c = idx - r * STRB;
        Wb[idx] = (r < H && c < H) ? f2b(W[r * H + c]) : 0;
    }
}

// ---------------------------------------------------------------------------
// MFMA NT GEMM, BM=128 x BN=64, 1-D grid bn-fast + bijective XCD swizzle.
// Epilogue: acc -> bf16 LDS tile [128][70] -> row-major vectorized I/O.
// ---------------------------------------------------------------------------
#define BM 128
#define BN 64
#define BK 32
#define LDP 40
#define STP 70   // epilogue staging stride (u16)
#define NXCD 8

__global__ __launch_bounds__(256) void k_gemm_fused(
        const u16* __restrict__ Xb,
        const u16* __restrict__ Wb,
        u16* __restrict__ outb,
        const float* __restrict__ hwbias,
        const u16* __restrict__ xnewb, const float* __restrict__ xnewf,
        const u16* __restrict__ xold,
        float* __restrict__ outf, long ostride,
        u16* __restrict__ mirror,
        int n_rows) {
    __shared__ __align__(16) char smem[BM * STP * 2];   // 17920 B
    short* As = (short*)smem;                           // [BM][LDP]
    short* Bs = (short*)(smem + BM * LDP * 2);          // [BN][LDP]
    u16*   St = (u16*)smem;                             // [BM][STP] (epilogue)
    const int tid = threadIdx.x;

    const int nwg = gridDim.x;
    const int q = nwg / NXCD, r = nwg % NXCD;
    const int xcd = blockIdx.x % NXCD, idx = blockIdx.x / NXCD;
    const int wgid = (xcd < r ? xcd * (q + 1) : r * (q + 1) + (xcd - r) * q) + idx;
    const int bm = (wgid / 5) * BM;
    const int bn = (wgid % 5) * BN;

    const int lane = tid & 63;
    const int wid = tid >> 6;
    const int wr = wid >> 1;
    const int wc = wid & 1;
    const int lrow = lane & 15;
    const int kgrp = lane >> 4;

    f32x4 acc[4][2];
    #pragma unroll
    for (int m = 0; m < 4; m++)
        #pragma unroll
        for (int n = 0; n < 2; n++) acc[m][n] = (f32x4){0.f, 0.f, 0.f, 0.f};

    for (int k0 = 0; k0 < STRB; k0 += BK) {
        #pragma unroll
        for (int i = 0; i < 2; ++i) {
            int qq = tid + i * 256;
            int rr = qq >> 2, c = (qq & 3) << 3;
            int gr = bm + rr;
            u16x8 v = {0, 0, 0, 0, 0, 0, 0, 0};
            if (gr < n_rows) v = *(const u16x8*)&Xb[(long)gr * STRB + k0 + c];
            *(u16x8*)&As[rr * LDP + c] = v;
        }
        {
            int rr = tid >> 2, c = (tid & 3) << 3;
            u16x8 v = *(const u16x8*)&Wb[(long)(bn + rr) * STRB + k0 + c];
            *(u16x8*)&Bs[rr * LDP + c] = v;
        }
        __syncthreads();

        bf16x8 af[4], bfr[2];
        #pragma unroll
        for (int m = 0; m < 4; m++) {
            int row = wr * 64 + m * 16 + lrow;
            af[m] = *(const bf16x8*)&As[row * LDP + kgrp * 8];
        }
        #pragma unroll
        for (int n = 0; n < 2; n++) {
            int col = wc * 32 + n * 16 + lrow;
            bfr[n] = *(const bf16x8*)&Bs[col * LDP + kgrp * 8];
        }
        #pragma unroll
        for (int m = 0; m < 4; m++)
            #pragma unroll
            for (int n = 0; n < 2; n++)
                acc[m][n] = __builtin_amdgcn_mfma_f32_16x16x32_bf16(af[m], bfr[n], acc[m][n], 0, 0, 0);
        __syncthreads();
    }

    // stage acc (bf16) into LDS tile [128][STP]
    #pragma unroll
    for (int m = 0; m < 4; m++)
        #pragma unroll
        for (int n = 0; n < 2; n++) {
            int lc = wc * 32 + n * 16 + lrow;
            #pragma unroll
            for (int rr = 0; rr < 4; rr++) {
                int row = wr * 64 + m * 16 + kgrp * 4 + rr;
                St[row * STP + lc] = f2b(acc[m][n][rr]);
            }
        }
    __syncthreads();

    // vectorized epilogue: 8 threads/row, 4 passes of 32 rows
    #pragma unroll
    for (int p = 0; p < 4; p++) {
        int row = p * 32 + (tid >> 3);
        int gr = bm + row;
        if (gr >= n_rows) continue;
        int lc0 = (tid & 7) * 8;
        int gc0 = bn + lc0;
        u16x8 pv = *(const u16x8*)&St[row * STP + lc0];
        if (outb) {
            u16x8 o;
            #pragma unroll
            for (int j = 0; j < 8; j++) o[j] = (gc0 + j < H) ? pv[j] : (u16)0;
            *(u16x8*)&outb[(long)gr * STRB + gc0] = o;
        } else {
            u16x8 xov = *(const u16x8*)&xold[(long)gr * STRB + gc0];
            float xn[8];
            if (xnewb) {
                u16x8 xnv = *(const u16x8*)&xnewb[(long)gr * STRB + gc0];
                #pragma unroll
                for (int j = 0; j < 8; j++) xn[j] = b2f(xnv[j]);
            } else {
                f32x4 a = *(const f32x4*)&xnewf[(long)gr * H + gc0];
                f32x4 b = *(const f32x4*)&xnewf[(long)gr * H + gc0 + 4];
                xn[0] = a[0]; xn[1] = a[1]; xn[2] = a[2]; xn[3] = a[3];
                xn[4] = b[0]; xn[5] = b[1]; xn[6] = b[2]; xn[7] = b[3];
            }
            float val[8];
            #pragma unroll
            for (int j = 0; j < 8; j++) {
                int gcj = gc0 + j;
                if (gcj < H) {
                    float pre = b2f(pv[j]) + hwbias[gcj];
                    float g = 1.0f / (1.0f + __expf(-pre));
                    val[j] = g * xn[j] + (1.0f - g) * b2f(xov[j]);
                } else val[j] = 0.f;
            }
            if (outf) {
                if (gc0 < H)
                    *(f32x4*)&outf[(long)gr * ostride + gc0] = (f32x4){val[0], val[1], val[2], val[3]};
                if (gc0 + 4 < H)
                    *(f32x4*)&outf[(long)gr * ostride + gc0 + 4] = (f32x4){val[4], val[5], val[6], val[7]};
            }
            if (mirror) {
                u16x8 mv;
                #pragma unroll
                for (int j = 0; j < 8; j++) mv[j] = f2b(val[j]);
                *(u16x8*)&mirror[(long)gr * STRB + gc0] = mv;
            }
        }
    }
}

// ---------------------------------------------------------------------------
// GCN gather, wave-per-node, unroll-8 edge pipeline. No LDS, no barriers.
// ---------------------------------------------------------------------------
__global__ __launch_bounds__(256) void k_gcn_gather_w(const u16* __restrict__ xb,
                                                      const float* __restrict__ dinv,
                                                      const int* __restrict__ offs,
                                                      const int* __restrict__ csr,
                                                      u16* __restrict__ outb, int n) {
    int node = blockIdx.x * 4 + (threadIdx.x >> 6);
    int lane = threadIdx.x & 63;
    if (node >= n) return;
    int start = offs[node], end = offs[node + 1];
    float acc[8];
    #pragma unroll
    for (int j = 0; j < 8; j++) acc[j] = 0.f;
    float di = dinv[node];
    const u16* rowp = xb + lane * 8;
    for (int tb = start; tb < end; tb += 64) {
        int p = tb + lane;
        int src = 0; float w = 0.f;
        if (p < end) {
            src = csr[p];
            w = di * dinv[src];
        }
        int cnt = min(64, end - tb);
        int qq = 0;
        for (; qq + 8 <= cnt; qq += 8) {
            float wv[8]; int sv[8];
            #pragma unroll
            for (int u = 0; u < 8; u++) {
                wv[u] = __shfl(w, qq + u);
                sv[u] = __shfl(src, qq + u);
            }
            if (lane < 40) {
                u16x8 vv[8];
                #pragma unroll
                for (int u = 0; u < 8; u++) vv[u] = *(const u16x8*)&rowp[(long)sv[u] * STRB];
                #pragma unroll
                for (int u = 0; u < 8; u++)
                    #pragma unroll
                    for (int j = 0; j < 8; j++) acc[j] += wv[u] * b2f(vv[u][j]);
            }
        }
        for (; qq < cnt; qq++) {
            float wq = __shfl(w, qq);
            int sq = __shfl(src, qq);
            if (lane < 40) {
                u16x8 v = *(const u16x8*)&rowp[(long)sq * STRB];
                #pragma unroll
                for (int j = 0; j < 8; j++) acc[j] += wq * b2f(v[j]);
            }
        }
    }
    if (lane < 40) {
        u16x8 o;
        #pragma unroll
        for (int j = 0; j < 8; j++) o[j] = f2b(fmaxf(acc[j], 0.f));
        *(u16x8*)&outb[(long)node * STRB + lane * 8] = o;
    }
}

// ---------------------------------------------------------------------------
// dual dot from bf16 mirror: one wave per row
// ---------------------------------------------------------------------------
__global__ void k_dual_dot_b(const u16* __restrict__ xb,
                             const float* __restrict__ ai, const float* __restrict__ aj,
                             float* __restrict__ s_i, float* __restrict__ s_j, int n) {
    int wave = blockIdx.x * (blockDim.x / WAVE) + (threadIdx.x >> 6);
    int lane = threadIdx.x & 63;
    if (wave >= n) return;
    const u16* row = xb + (long)wave * STRB;
    float d0 = 0.f, d1 = 0.f;
    {
        u16x4 v = *(const u16x4*)&row[lane * 4];
        float4 a4 = *(const float4*)&ai[lane * 4];
        float4 j4 = *(const float4*)&aj[lane * 4];
        float x0 = b2f(v[0]), x1 = b2f(v[1]), x2 = b2f(v[2]), x3 = b2f(v[3]);
        d0 = x0 * a4.x + x1 * a4.y + x2 * a4.z + x3 * a4.w;
        d1 = x0 * j4.x + x1 * j4.y + x2 * j4.z + x3 * j4.w;
    }
    if (lane < 11) {
        u16x4 v = *(const u16x4*)&row[256 + lane * 4];
        float4 a4 = *(const float4*)&ai[256 + lane * 4];
        float4 j4 = *(const float4*)&aj[256 + lane * 4];
        float x0 = b2f(v[0]), x1 = b2f(v[1]), x2 = b2f(v[2]), x3 = b2f(v[3]);
        d0 += x0 * a4.x + x1 * a4.y + x2 * a4.z + x3 * a4.w;
        d1 += x0 * j4.x + x1 * j4.y + x2 * j4.z + x3 * j4.w;
    }
    for (int o = 32; o > 0; o >>= 1) { d0 += __shfl_down(d0, o); d1 += __shfl_down(d1, o); }
    if (lane == 0) { s_i[wave] = d0; s_j[wave] = d1; }
}

// ---------------------------------------------------------------------------
// GAT gather, wave-per-node, fused softmax + unroll-8 edge pipeline.
// ---------------------------------------------------------------------------
__global__ __launch_bounds__(256) void k_gat_gather_w(const u16* __restrict__ xb,
                                                      const float* __restrict__ s_i_arr,
                                                      const float* __restrict__ s_j_arr,
                                                      const int* __restrict__ offs,
                                                      const int* __restrict__ csr,
                                                      u16* __restrict__ outb16,
                                                      float* __restrict__ outf, long out_stride,
                                                      int out_off, int n) {
    int node = blockIdx.x * 4 + (threadIdx.x >> 6);
    int lane = threadIdx.x & 63;
    if (node >= n) return;
    int start = offs[node], end = offs[node + 1];
    int deg = end - start;
    float acc[8];
    #pragma unroll
    for (int j = 0; j < 8; j++) acc[j] = 0.f;

    if (deg > 0) {
        float si = s_i_arr[node];
        float m_t = -1e30f, s_t = 0.f;
        for (int p = start + lane; p < end; p += 64) {
            float sc = si + s_j_arr[csr[p]];
            sc = (sc >= 0.f) ? sc : 0.01f * sc;
            if (sc > m_t) { s_t = s_t * __expf(m_t - sc) + 1.0f; m_t = sc; }
            else s_t += __expf(sc - m_t);
        }
        for (int o = 32; o > 0; o >>= 1) {
            float m2 = __shfl_xor(m_t, o), s2 = __shfl_xor(s_t, o);
            float mm = fmaxf(m_t, m2);
            s_t = s_t * __expf(m_t - mm) + s2 * __expf(m2 - mm);
            m_t = mm;
        }
        float m = m_t;
        float inv = 1.0f / (s_t + 1e-16f);
        const u16* rowp = xb + lane * 8;
        for (int tb = start; tb < end; tb += 64) {
            int p = tb + lane;
            int src = 0; float w = 0.f;
            if (p < end) {
                src = csr[p];
                float sc = si + s_j_arr[src];
                sc = (sc >= 0.f) ? sc : 0.01f * sc;
                w = __expf(sc - m) * inv;
            }
            int cnt = min(64, end - tb);
            int qq = 0;
            for (; qq + 8 <= cnt; qq += 8) {
                float wv[8]; int sv[8];
                #pragma unroll
                for (int u = 0; u < 8; u++) {
                    wv[u] = __shfl(w, qq + u);
                    sv[u] = __shfl(src, qq + u);
                }
                if (lane < 40) {
                    u16x8 vv[8];
                    #pragma unroll
                    for (int u = 0; u < 8; u++) vv[u] = *(const u16x8*)&rowp[(long)sv[u] * STRB];
                    #pragma unroll
                    for (int u = 0; u < 8; u++)
                        #pragma unroll
                        for (int j = 0; j < 8; j++) acc[j] += wv[u] * b2f(vv[u][j]);
                }
            }
            for (; qq < cnt; qq++) {
                float wq = __shfl(w, qq);
                int sq = __shfl(src, qq);
                if (lane < 40) {
                    u16x8 v = *(const u16x8*)&rowp[(long)sq * STRB];
                    #pragma unroll
                    for (int j = 0; j < 8; j++) acc[j] += wq * b2f(v[j]);
                }
            }
        }
    }
    if (outb16) {
        if (lane < 40) {
            u16x8 o;
            #pragma unroll
            for (int j = 0; j < 8; j++) o[j] = f2b(fmaxf(acc[j], 0.f));
            *(u16x8*)&outb16[(long)node * STRB + lane * 8] = o;
        }
    } else {
        if (lane < 38) {
            #pragma unroll
            for (int j = 0; j < 8; j++) {
                int c = lane * 8 + j;
                if (c < H) outf[(long)node * out_stride + out_off + c] = fmaxf(acc[j], 0.f);
            }
        }
    }
}

// ---------------------------------------------------------------------------
// launch
// ---------------------------------------------------------------------------
extern "C" void kernel_launch(void* const* d_in, const int* in_sizes, int n_in,
                              void* d_out, int out_size, void* d_ws, size_t ws_size,
                              hipStream_t stream) {
    const float* x_e     = (const float*)d_in[0];
    const int*   ei_all  = (const int*)d_in[3];
    const float* gcn1_W  = (const float*)d_in[5];
    const float* hw1_W   = (const float*)d_in[6];
    const float* hw1_b   = (const float*)d_in[7];
    const float* gat1_ai = (const float*)d_in[8];
    const float* gat1_aj = (const float*)d_in[9];
    const float* ghw1_W  = (const float*)d_in[10];
    const float* ghw1_b  = (const float*)d_in[11];
    const float* gat2_ai = (const float*)d_in[12];
    const float* gat2_aj = (const float*)d_in[13];
    const float* ghw2_W  = (const float*)d_in[14];
    const float* ghw2_b  = (const float*)d_in[15];
    const float* gat_ai  = (const float*)d_in[16];
    const float* gat_aj  = (const float*)d_in[17];

    const int N = in_sizes[0] / H;
    const int E = in_sizes[3] / 2;
    const int* ei_j = ei_all;
    const int* ei_i = ei_all + E;

    float* out = (float*)d_out;

    size_t NSB = (size_t)N * STRB;
    u16*   W0   = (u16*)d_ws;
    u16*   W1   = W0 + NSB;
    u16*   W2   = W1 + NSB;
    u16*   W3   = W2 + NSB;
    float* G2F  = (float*)d_ws;              // spans [0, 60MB) ⊂ W0+W1 (64MB)
    float* sbi  = (float*)(W3 + NSB);
    float* sbj  = sbi + N;
    float* dinv = sbj + N;
    int*   deg  = (int*)(dinv + N);
    int*   offs = deg + N;                   // N+1
    int*   cursor = offs + (N + 1);
    int*   csr  = cursor + N;                // E ints
    int*   btot = csr + E;                   // 64
    int*   bpre = btot + 64;                 // 64
    u16*   wb0  = (u16*)(bpre + 64);         // 4 x 320x320 bf16 weights
    u16*   wb1  = wb0 + STRB * STRB;
    u16*   wb2  = wb1 + STRB * STRB;
    u16*   wb3  = wb2 + STRB * STRB;

    dim3 blk256(256);
    int rowsPerBlock = 256 / WAVE;
    dim3 gridRows((N + rowsPerBlock - 1) / rowsPerBlock);
    dim3 gridNodeW((N + 3) / 4);
    dim3 gridE(2048);
    dim3 gridW(400);
    dim3 gridGemm(((N + BM - 1) / BM) * 5);
    int nScanB = (N + SCB - 1) / SCB;

    // 1. x0b = bf16(l2_normalize(x_e)) -> W0
    hipLaunchKernelGGL(k_l2norm, gridRows, blk256, 0, stream, x_e, W0, N);

    // 2. CSR build + weight conversion
    hipLaunchKernelGGL(k_zero_int, dim3(256), blk256, 0, stream, deg, N);
    hipLaunchKernelGGL(k_count_deg, gridE, blk256, 0, stream, ei_i, deg, E);
    hipLaunchKernelGGL(k_scan_local, dim3(nScanB), dim3(SCB), 0, stream, deg, offs, btot, dinv, N);
    hipLaunchKernelGGL(k_scan_tots, dim3(1), dim3(64), 0, stream, btot, bpre, nScanB, offs + N);
    hipLaunchKernelGGL(k_scan_apply, dim3(256), blk256, 0, stream, offs, bpre, cursor, N);
    hipLaunchKernelGGL(k_fill_csr, gridE, blk256, 0, stream, ei_j, ei_i, cursor, csr, E);
    hipLaunchKernelGGL(k_conv_w4, gridW, blk256, 0, stream,
                       gcn1_W, hw1_W, ghw1_W, ghw2_W, wb0, wb1, wb2, wb3);

    // 3. hb = bf16(x0 @ gcn1_W.T) -> W1
    hipLaunchKernelGGL(k_gemm_fused, gridGemm, blk256, 0, stream,
                       W0, wb0, W1,
                       (const float*)nullptr, (const u16*)nullptr, (const float*)nullptr,
                       (const u16*)nullptr, (float*)nullptr, (long)0, (u16*)nullptr, N);

    // 4. gcnb -> W2
    hipLaunchKernelGGL(k_gcn_gather_w, gridNodeW, blk256, 0, stream, W1, dinv, offs, csr, W2, N);

    // 5. x2b = hw(x0b, gcnb) fused: pre = x0b@hw1_W.T -> mirror W3
    hipLaunchKernelGGL(k_gemm_fused, gridGemm, blk256, 0, stream,
                       W0, wb1, (u16*)nullptr,
                       hw1_b, W2, (const float*)nullptr, W0,
                       (float*)nullptr, (long)0, W3, N);

    // 6. dots for GAT1 from x2b
    hipLaunchKernelGGL(k_dual_dot_b, gridRows, blk256, 0, stream, W3, gat1_ai, gat1_aj, sbi, sbj, N);

    // 7. GAT1 gather on x2b -> g1b (W1)
    hipLaunchKernelGGL(k_gat_gather_w, gridNodeW, blk256, 0, stream, W3, sbi, sbj, offs, csr,
                       W1, (float*)nullptr, (long)0, 0, N);

    // 8. x3b = hw(x2b, g1b) fused: pre = x2b@ghw1_W.T -> mirror W2
    hipLaunchKernelGGL(k_gemm_fused, gridGemm, blk256, 0, stream,
                       W3, wb2, (u16*)nullptr,
                       ghw1_b, W1, (const float*)nullptr, W3,
                       (float*)nullptr, (long)0, W2, N);

    // 9. dots for GAT2 from x3b
    hipLaunchKernelGGL(k_dual_dot_b, gridRows, blk256, 0, stream, W2, gat2_ai, gat2_aj, sbi, sbj, N);

    // 10. GAT2 gather on x3b -> G2F (fp32, contiguous stride H)
    hipLaunchKernelGGL(k_gat_gather_w, gridNodeW, blk256, 0, stream, W2, sbi, sbj, offs, csr,
                       (u16*)nullptr, G2F, (long)H, 0, N);

    // 11. xe = hw(x2b, G2F) fused: pre = x2b@ghw2_W.T -> d_out[:,0:300] fp32 + mirror xeb (W2)
    hipLaunchKernelGGL(k_gemm_fused, gridGemm, blk256, 0, stream,
                       W3, wb3, (u16*)nullptr,
                       ghw2_b, (const u16*)nullptr, G2F, W3,
                       out, (long)(2 * H), W2, N);

    // 12. dots for final GAT from xeb
    hipLaunchKernelGGL(k_dual_dot_b, gridRows, blk256, 0, stream, W2, gat_ai, gat_aj, sbi, sbj, N);

    // 13. final GAT gather on xeb -> d_out[:,300:600]
    hipLaunchKernelGGL(k_gat_gather_w, gridNodeW, blk256, 0, stream, W2, sbi, sbj, offs, csr,
                       (u16*)nullptr, out, (long)(2 * H), H, N);
}

// Round 15
// 665.763 us; speedup vs baseline: 1.0611x; 1.0262x over previous
//
#include <hip/hip_runtime.h>
#include <hip/hip_bf16.h>
#include <math.h>

#define H 300
#define WAVE 64
#define STRB 320   // padded bf16 row stride (640 B; 40 chunks of 16 B)
#define SCB 1024

typedef short bf16x8 __attribute__((ext_vector_type(8)));
typedef unsigned short u16;
typedef u16 u16x8 __attribute__((ext_vector_type(8)));
typedef u16 u16x4 __attribute__((ext_vector_type(4)));
typedef float f32x4 __attribute__((ext_vector_type(4)));

__device__ inline unsigned short f2b(float f) {
    union { float f; unsigned int u; } x; x.f = f;
    unsigned int r = x.u + 0x7FFF + ((x.u >> 16) & 1);
    return (unsigned short)(r >> 16);
}
__device__ inline float b2f(u16 h) {
    union { float f; unsigned int u; } x; x.u = ((unsigned int)h) << 16;
    return x.f;
}

// ---------------------------------------------------------------------------
// l2 normalize rows: one wave per row; bf16 padded output only
// ---------------------------------------------------------------------------
__global__ void k_l2norm(const float* __restrict__ x, u16* __restrict__ outb, int n) {
    int wave = blockIdx.x * (blockDim.x / WAVE) + (threadIdx.x >> 6);
    int lane = threadIdx.x & 63;
    if (wave >= n) return;
    const float* row = x + (long)wave * H;
    float s = 0.f;
    for (int j = lane; j < H; j += WAVE) { float v = row[j]; s += v * v; }
    for (int o = 32; o > 0; o >>= 1) s += __shfl_xor(s, o);
    float sc = 1.0f / fmaxf(sqrtf(s), 1e-12f);
    u16* brow = outb + (long)wave * STRB;
    for (int j = lane; j < H; j += WAVE) brow[j] = f2b(row[j] * sc);
    for (int j = H + lane; j < STRB; j += WAVE) brow[j] = 0;
}

__global__ void k_zero_int(int* p, int n) {
    int i = blockIdx.x * blockDim.x + threadIdx.x;
    int stride = gridDim.x * blockDim.x;
    for (; i < n; i += stride) p[i] = 0;
}

__global__ void k_count_deg(const int* __restrict__ ei_i, int* __restrict__ deg, int E) {
    int i = blockIdx.x * blockDim.x + threadIdx.x;
    int stride = gridDim.x * blockDim.x;
    for (; i < E; i += stride) atomicAdd(&deg[ei_i[i]], 1);
}

// ---------------------------------------------------------------------------
// parallel exclusive scan of deg -> offs(+cursor), offs[n]=total; dinv fused
// ---------------------------------------------------------------------------
__global__ void k_scan_local(const int* __restrict__ deg, int* __restrict__ offs,
                             int* __restrict__ btot, float* __restrict__ dinv, int n) {
    __shared__ int sh[SCB];
    int base = blockIdx.x * SCB;
    int tid = threadIdx.x;
    int v = (base + tid < n) ? deg[base + tid] : 0;
    if (base + tid < n) dinv[base + tid] = (v > 0) ? 1.0f / sqrtf((float)v) : 0.0f;
    sh[tid] = v;
    __syncthreads();
    for (int off = 1; off < SCB; off <<= 1) {
        int add = (tid >= off) ? sh[tid - off] : 0;
        __syncthreads();
        sh[tid] += add;
        __syncthreads();
    }
    if (base + tid < n) offs[base + tid] = sh[tid] - v;
    if (tid == SCB - 1) btot[blockIdx.x] = sh[tid];
}

__global__ void k_scan_tots(const int* __restrict__ btot, int* __restrict__ bpre,
                            int nb, int* __restrict__ total_out) {
    int l = threadIdx.x;   // single wave of 64; nb <= 64
    int v = (l < nb) ? btot[l] : 0;
    int own = v;
    for (int o = 1; o < 64; o <<= 1) {
        int u = __shfl_up(v, o);
        if (l >= o) v += u;
    }
    if (l < nb) bpre[l] = v - own;
    if (l == 63) total_out[0] = v;
}

__global__ void k_scan_apply(int* __restrict__ offs, const int* __restrict__ bpre,
                             int* __restrict__ cursor, int n) {
    int i = blockIdx.x * blockDim.x + threadIdx.x;
    int stride = gridDim.x * blockDim.x;
    for (; i < n; i += stride) {
        int o = offs[i] + bpre[i / SCB];
        offs[i] = o;
        cursor[i] = o;
    }
}

__global__ void k_fill_csr(const int* __restrict__ ei_j, const int* __restrict__ ei_i,
                           int* __restrict__ cursor, int* __restrict__ csr_src, int E) {
    int i = blockIdx.x * blockDim.x + threadIdx.x;
    int stride = gridDim.x * blockDim.x;
    for (; i < E; i += stride) {
        int dst = ei_i[i];
        int pos = atomicAdd(&cursor[dst], 1);
        csr_src[pos] = ei_j[i];
    }
}

// ---------------------------------------------------------------------------
// 4x W fp32 [300][300] -> padded bf16 [320][320], pads zero. One launch.
// ---------------------------------------------------------------------------
__global__ void k_conv_w4(const float* __restrict__ W0f, const float* __restrict__ W1f,
                          const float* __restrict__ W2f, const float* __restrict__ W3f,
                          u16* __restrict__ Wb0, u16* __restrict__ Wb1,
                          u16* __restrict__ Wb2, u16* __restrict__ Wb3) {
    int which = blockIdx.x & 3;
    const float* W = (which == 0) ? W0f : (which == 1) ? W1f : (which == 2) ? W2f : W3f;
    u16* Wb = (which == 0) ? Wb0 : (which == 1) ? Wb1 : (which == 2) ? Wb2 : Wb3;
    int idx = (blockIdx.x >> 2) * blockDim.x + threadIdx.x;
    int stride = (gridDim.x >> 2) * blockDim.x;
    for (; idx < STRB * STRB; idx += stride) {
        int r = idx / STRB, c = idx - r * STRB;
        Wb[idx] = (r < H && c < H) ? f2b(W[r * H + c]) : 0;
    }
}

// ---------------------------------------------------------------------------
// MFMA NT GEMM, BM=128 x BN=64, 1-D grid bn-fast + bijective XCD swizzle.
// Epilogue: acc -> bf16 LDS tile [128][70] -> row-major vectorized I/O.
// ---------------------------------------------------------------------------
#define BM 128
#define BN 64
#define BK 32
#define LDP 40
#define STP 70   // epilogue staging stride (u16)
#define NXCD 8

__global__ __launch_bounds__(256) void k_gemm_fused(
        const u16* __restrict__ Xb,
        const u16* __restrict__ Wb,
        u16* __restrict__ outb,
        const float* __restrict__ hwbias,
        const u16* __restrict__ xnewb, const float* __restrict__ xnewf,
        const u16* __restrict__ xold,
        float* __restrict__ outf, long ostride,
        u16* __restrict__ mirror,
        int n_rows) {
    __shared__ __align__(16) char smem[BM * STP * 2];   // 17920 B
    short* As = (short*)smem;                           // [BM][LDP]
    short* Bs = (short*)(smem + BM * LDP * 2);          // [BN][LDP]
    u16*   St = (u16*)smem;                             // [BM][STP] (epilogue)
    const int tid = threadIdx.x;

    const int nwg = gridDim.x;
    const int q = nwg / NXCD, r = nwg % NXCD;
    const int xcd = blockIdx.x % NXCD, idx = blockIdx.x / NXCD;
    const int wgid = (xcd < r ? xcd * (q + 1) : r * (q + 1) + (xcd - r) * q) + idx;
    const int bm = (wgid / 5) * BM;
    const int bn = (wgid % 5) * BN;

    const int lane = tid & 63;
    const int wid = tid >> 6;
    const int wr = wid >> 1;
    const int wc = wid & 1;
    const int lrow = lane & 15;
    const int kgrp = lane >> 4;

    f32x4 acc[4][2];
    #pragma unroll
    for (int m = 0; m < 4; m++)
        #pragma unroll
        for (int n = 0; n < 2; n++) acc[m][n] = (f32x4){0.f, 0.f, 0.f, 0.f};

    for (int k0 = 0; k0 < STRB; k0 += BK) {
        #pragma unroll
        for (int i = 0; i < 2; ++i) {
            int qq = tid + i * 256;
            int rr = qq >> 2, c = (qq & 3) << 3;
            int gr = bm + rr;
            u16x8 v = {0, 0, 0, 0, 0, 0, 0, 0};
            if (gr < n_rows) v = *(const u16x8*)&Xb[(long)gr * STRB + k0 + c];
            *(u16x8*)&As[rr * LDP + c] = v;
        }
        {
            int rr = tid >> 2, c = (tid & 3) << 3;
            u16x8 v = *(const u16x8*)&Wb[(long)(bn + rr) * STRB + k0 + c];
            *(u16x8*)&Bs[rr * LDP + c] = v;
        }
        __syncthreads();

        bf16x8 af[4], bfr[2];
        #pragma unroll
        for (int m = 0; m < 4; m++) {
            int row = wr * 64 + m * 16 + lrow;
            af[m] = *(const bf16x8*)&As[row * LDP + kgrp * 8];
        }
        #pragma unroll
        for (int n = 0; n < 2; n++) {
            int col = wc * 32 + n * 16 + lrow;
            bfr[n] = *(const bf16x8*)&Bs[col * LDP + kgrp * 8];
        }
        #pragma unroll
        for (int m = 0; m < 4; m++)
            #pragma unroll
            for (int n = 0; n < 2; n++)
                acc[m][n] = __builtin_amdgcn_mfma_f32_16x16x32_bf16(af[m], bfr[n], acc[m][n], 0, 0, 0);
        __syncthreads();
    }

    // stage acc (bf16) into LDS tile [128][STP]
    #pragma unroll
    for (int m = 0; m < 4; m++)
        #pragma unroll
        for (int n = 0; n < 2; n++) {
            int lc = wc * 32 + n * 16 + lrow;
            #pragma unroll
            for (int rr = 0; rr < 4; rr++) {
                int row = wr * 64 + m * 16 + kgrp * 4 + rr;
                St[row * STP + lc] = f2b(acc[m][n][rr]);
            }
        }
    __syncthreads();

    // vectorized epilogue: 8 threads/row, 4 passes of 32 rows
    #pragma unroll
    for (int p = 0; p < 4; p++) {
        int row = p * 32 + (tid >> 3);
        int gr = bm + row;
        if (gr >= n_rows) continue;
        int lc0 = (tid & 7) * 8;
        int gc0 = bn + lc0;
        u16x8 pv = *(const u16x8*)&St[row * STP + lc0];
        if (outb) {
            u16x8 o;
            #pragma unroll
            for (int j = 0; j < 8; j++) o[j] = (gc0 + j < H) ? pv[j] : (u16)0;
            *(u16x8*)&outb[(long)gr * STRB + gc0] = o;
        } else {
            u16x8 xov = *(const u16x8*)&xold[(long)gr * STRB + gc0];
            float xn[8];
            if (xnewb) {
                u16x8 xnv = *(const u16x8*)&xnewb[(long)gr * STRB + gc0];
                #pragma unroll
                for (int j = 0; j < 8; j++) xn[j] = b2f(xnv[j]);
            } else {
                f32x4 a = *(const f32x4*)&xnewf[(long)gr * H + gc0];
                f32x4 b = *(const f32x4*)&xnewf[(long)gr * H + gc0 + 4];
                xn[0] = a[0]; xn[1] = a[1]; xn[2] = a[2]; xn[3] = a[3];
                xn[4] = b[0]; xn[5] = b[1]; xn[6] = b[2]; xn[7] = b[3];
            }
            float val[8];
            #pragma unroll
            for (int j = 0; j < 8; j++) {
                int gcj = gc0 + j;
                if (gcj < H) {
                    float pre = b2f(pv[j]) + hwbias[gcj];
                    float g = 1.0f / (1.0f + __expf(-pre));
                    val[j] = g * xn[j] + (1.0f - g) * b2f(xov[j]);
                } else val[j] = 0.f;
            }
            if (outf) {
                if (gc0 < H)
                    *(f32x4*)&outf[(long)gr * ostride + gc0] = (f32x4){val[0], val[1], val[2], val[3]};
                if (gc0 + 4 < H)
                    *(f32x4*)&outf[(long)gr * ostride + gc0 + 4] = (f32x4){val[4], val[5], val[6], val[7]};
            }
            if (mirror) {
                u16x8 mv;
                #pragma unroll
                for (int j = 0; j < 8; j++) mv[j] = f2b(val[j]);
                *(u16x8*)&mirror[(long)gr * STRB + gc0] = mv;
            }
        }
    }
}

// ---------------------------------------------------------------------------
// GCN gather, wave-per-node, unroll-4 edge pipeline. No LDS, no barriers.
// ---------------------------------------------------------------------------
__global__ __launch_bounds__(256) void k_gcn_gather_w(const u16* __restrict__ xb,
                                                      const float* __restrict__ dinv,
                                                      const int* __restrict__ offs,
                                                      const int* __restrict__ csr,
                                                      u16* __restrict__ outb, int n) {
    int node = blockIdx.x * 4 + (threadIdx.x >> 6);
    int lane = threadIdx.x & 63;
    if (node >= n) return;
    int start = offs[node], end = offs[node + 1];
    float acc[8];
    #pragma unroll
    for (int j = 0; j < 8; j++) acc[j] = 0.f;
    float di = dinv[node];
    const u16* rowp = xb + lane * 8;
    for (int tb = start; tb < end; tb += 64) {
        int p = tb + lane;
        int src = 0; float w = 0.f;
        if (p < end) {
            src = csr[p];
            w = di * dinv[src];
        }
        int cnt = min(64, end - tb);
        int qq = 0;
        for (; qq + 4 <= cnt; qq += 4) {
            float w0 = __shfl(w, qq), w1 = __shfl(w, qq + 1);
            float w2 = __shfl(w, qq + 2), w3 = __shfl(w, qq + 3);
            int s0 = __shfl(src, qq), s1 = __shfl(src, qq + 1);
            int s2 = __shfl(src, qq + 2), s3 = __shfl(src, qq + 3);
            if (lane < 40) {
                u16x8 v0 = *(const u16x8*)&rowp[(long)s0 * STRB];
                u16x8 v1 = *(const u16x8*)&rowp[(long)s1 * STRB];
                u16x8 v2 = *(const u16x8*)&rowp[(long)s2 * STRB];
                u16x8 v3 = *(const u16x8*)&rowp[(long)s3 * STRB];
                #pragma unroll
                for (int j = 0; j < 8; j++) acc[j] += w0 * b2f(v0[j]);
                #pragma unroll
                for (int j = 0; j < 8; j++) acc[j] += w1 * b2f(v1[j]);
                #pragma unroll
                for (int j = 0; j < 8; j++) acc[j] += w2 * b2f(v2[j]);
                #pragma unroll
                for (int j = 0; j < 8; j++) acc[j] += w3 * b2f(v3[j]);
            }
        }
        for (; qq < cnt; qq++) {
            float wq = __shfl(w, qq);
            int sq = __shfl(src, qq);
            if (lane < 40) {
                u16x8 v = *(const u16x8*)&rowp[(long)sq * STRB];
                #pragma unroll
                for (int j = 0; j < 8; j++) acc[j] += wq * b2f(v[j]);
            }
        }
    }
    if (lane < 40) {
        u16x8 o;
        #pragma unroll
        for (int j = 0; j < 8; j++) o[j] = f2b(fmaxf(acc[j], 0.f));
        *(u16x8*)&outb[(long)node * STRB + lane * 8] = o;
    }
}

// ---------------------------------------------------------------------------
// dual dot from bf16 mirror: one wave per row
// ---------------------------------------------------------------------------
__global__ void k_dual_dot_b(const u16* __restrict__ xb,
                             const float* __restrict__ ai, const float* __restrict__ aj,
                             float* __restrict__ s_i, float* __restrict__ s_j, int n) {
    int wave = blockIdx.x * (blockDim.x / WAVE) + (threadIdx.x >> 6);
    int lane = threadIdx.x & 63;
    if (wave >= n) return;
    const u16* row = xb + (long)wave * STRB;
    float d0 = 0.f, d1 = 0.f;
    {
        u16x4 v = *(const u16x4*)&row[lane * 4];
        float4 a4 = *(const float4*)&ai[lane * 4];
        float4 j4 = *(const float4*)&aj[lane * 4];
        float x0 = b2f(v[0]), x1 = b2f(v[1]), x2 = b2f(v[2]), x3 = b2f(v[3]);
        d0 = x0 * a4.x + x1 * a4.y + x2 * a4.z + x3 * a4.w;
        d1 = x0 * j4.x + x1 * j4.y + x2 * j4.z + x3 * j4.w;
    }
    if (lane < 11) {
        u16x4 v = *(const u16x4*)&row[256 + lane * 4];
        float4 a4 = *(const float4*)&ai[256 + lane * 4];
        float4 j4 = *(const float4*)&aj[256 + lane * 4];
        float x0 = b2f(v[0]), x1 = b2f(v[1]), x2 = b2f(v[2]), x3 = b2f(v[3]);
        d0 += x0 * a4.x + x1 * a4.y + x2 * a4.z + x3 * a4.w;
        d1 += x0 * j4.x + x1 * j4.y + x2 * j4.z + x3 * j4.w;
    }
    for (int o = 32; o > 0; o >>= 1) { d0 += __shfl_down(d0, o); d1 += __shfl_down(d1, o); }
    if (lane == 0) { s_i[wave] = d0; s_j[wave] = d1; }
}

// ---------------------------------------------------------------------------
// GAT gather, wave-per-node, fused softmax + unroll-4 edge pipeline.
// ---------------------------------------------------------------------------
__global__ __launch_bounds__(256) void k_gat_gather_w(const u16* __restrict__ xb,
                                                      const float* __restrict__ s_i_arr,
                                                      const float* __restrict__ s_j_arr,
                                                      const int* __restrict__ offs,
                                                      const int* __restrict__ csr,
                                                      u16* __restrict__ outb16,
                                                      float* __restrict__ outf, long out_stride,
                                                      int out_off, int n) {
    int node = blockIdx.x * 4 + (threadIdx.x >> 6);
    int lane = threadIdx.x & 63;
    if (node >= n) return;
    int start = offs[node], end = offs[node + 1];
    int deg = end - start;
    float acc[8];
    #pragma unroll
    for (int j = 0; j < 8; j++) acc[j] = 0.f;

    if (deg > 0) {
        float si = s_i_arr[node];
        float m_t = -1e30f, s_t = 0.f;
        for (int p = start + lane; p < end; p += 64) {
            float sc = si + s_j_arr[csr[p]];
            sc = (sc >= 0.f) ? sc : 0.01f * sc;
            if (sc > m_t) { s_t = s_t * __expf(m_t - sc) + 1.0f; m_t = sc; }
            else s_t += __expf(sc - m_t);
        }
        for (int o = 32; o > 0; o >>= 1) {
            float m2 = __shfl_xor(m_t, o), s2 = __shfl_xor(s_t, o);
            float mm = fmaxf(m_t, m2);
            s_t = s_t * __expf(m_t - mm) + s2 * __expf(m2 - mm);
            m_t = mm;
        }
        float m = m_t;
        float inv = 1.0f / (s_t + 1e-16f);
        const u16* rowp = xb + lane * 8;
        for (int tb = start; tb < end; tb += 64) {
            int p = tb + lane;
            int src = 0; float w = 0.f;
            if (p < end) {
                src = csr[p];
                float sc = si + s_j_arr[src];
                sc = (sc >= 0.f) ? sc : 0.01f * sc;
                w = __expf(sc - m) * inv;
            }
            int cnt = min(64, end - tb);
            int qq = 0;
            for (; qq + 4 <= cnt; qq += 4) {
                float w0 = __shfl(w, qq), w1 = __shfl(w, qq + 1);
                float w2 = __shfl(w, qq + 2), w3 = __shfl(w, qq + 3);
                int s0 = __shfl(src, qq), s1 = __shfl(src, qq + 1);
                int s2 = __shfl(src, qq + 2), s3 = __shfl(src, qq + 3);
                if (lane < 40) {
                    u16x8 v0 = *(const u16x8*)&rowp[(long)s0 * STRB];
                    u16x8 v1 = *(const u16x8*)&rowp[(long)s1 * STRB];
                    u16x8 v2 = *(const u16x8*)&rowp[(long)s2 * STRB];
                    u16x8 v3 = *(const u16x8*)&rowp[(long)s3 * STRB];
                    #pragma unroll
                    for (int j = 0; j < 8; j++) acc[j] += w0 * b2f(v0[j]);
                    #pragma unroll
                    for (int j = 0; j < 8; j++) acc[j] += w1 * b2f(v1[j]);
                    #pragma unroll
                    for (int j = 0; j < 8; j++) acc[j] += w2 * b2f(v2[j]);
                    #pragma unroll
                    for (int j = 0; j < 8; j++) acc[j] += w3 * b2f(v3[j]);
                }
            }
            for (; qq < cnt; qq++) {
                float wq = __shfl(w, qq);
                int sq = __shfl(src, qq);
                if (lane < 40) {
                    u16x8 v = *(const u16x8*)&rowp[(long)sq * STRB];
                    #pragma unroll
                    for (int j = 0; j < 8; j++) acc[j] += wq * b2f(v[j]);
                }
            }
        }
    }
    if (outb16) {
        if (lane < 40) {
            u16x8 o;
            #pragma unroll
            for (int j = 0; j < 8; j++) o[j] = f2b(fmaxf(acc[j], 0.f));
            *(u16x8*)&outb16[(long)node * STRB + lane * 8] = o;
        }
    } else {
        if (lane < 38) {
            #pragma unroll
            for (int j = 0; j < 8; j++) {
                int c = lane * 8 + j;
                if (c < H) outf[(long)node * out_stride + out_off + c] = fmaxf(acc[j], 0.f);
            }
        }
    }
}

// ---------------------------------------------------------------------------
// launch
// ---------------------------------------------------------------------------
extern "C" void kernel_launch(void* const* d_in, const int* in_sizes, int n_in,
                              void* d_out, int out_size, void* d_ws, size_t ws_size,
                              hipStream_t stream) {
    const float* x_e     = (const float*)d_in[0];
    const int*   ei_all  = (const int*)d_in[3];
    const float* gcn1_W  = (const float*)d_in[5];
    const float* hw1_W   = (const float*)d_in[6];
    const float* hw1_b   = (const float*)d_in[7];
    const float* gat1_ai = (const float*)d_in[8];
    const float* gat1_aj = (const float*)d_in[9];
    const float* ghw1_W  = (const float*)d_in[10];
    const float* ghw1_b  = (const float*)d_in[11];
    const float* gat2_ai = (const float*)d_in[12];
    const float* gat2_aj = (const float*)d_in[13];
    const float* ghw2_W  = (const float*)d_in[14];
    const float* ghw2_b  = (const float*)d_in[15];
    const float* gat_ai  = (const float*)d_in[16];
    const float* gat_aj  = (const float*)d_in[17];

    const int N = in_sizes[0] / H;
    const int E = in_sizes[3] / 2;
    const int* ei_j = ei_all;
    const int* ei_i = ei_all + E;

    float* out = (float*)d_out;

    size_t NSB = (size_t)N * STRB;
    u16*   W0   = (u16*)d_ws;
    u16*   W1   = W0 + NSB;
    u16*   W2   = W1 + NSB;
    u16*   W3   = W2 + NSB;
    float* G2F  = (float*)d_ws;              // spans [0, 60MB) ⊂ W0+W1 (64MB)
    float* sbi  = (float*)(W3 + NSB);
    float* sbj  = sbi + N;
    float* dinv = sbj + N;
    int*   deg  = (int*)(dinv + N);
    int*   offs = deg + N;                   // N+1
    int*   cursor = offs + (N + 1);
    int*   csr  = cursor + N;                // E ints
    int*   btot = csr + E;                   // 64
    int*   bpre = btot + 64;                 // 64
    u16*   wb0  = (u16*)(bpre + 64);         // 4 x 320x320 bf16 weights
    u16*   wb1  = wb0 + STRB * STRB;
    u16*   wb2  = wb1 + STRB * STRB;
    u16*   wb3  = wb2 + STRB * STRB;

    dim3 blk256(256);
    int rowsPerBlock = 256 / WAVE;
    dim3 gridRows((N + rowsPerBlock - 1) / rowsPerBlock);
    dim3 gridNodeW((N + 3) / 4);
    dim3 gridE(2048);
    dim3 gridW(400);
    dim3 gridGemm(((N + BM - 1) / BM) * 5);
    int nScanB = (N + SCB - 1) / SCB;

    // 1. x0b = bf16(l2_normalize(x_e)) -> W0
    hipLaunchKernelGGL(k_l2norm, gridRows, blk256, 0, stream, x_e, W0, N);

    // 2. CSR build + weight conversion
    hipLaunchKernelGGL(k_zero_int, dim3(256), blk256, 0, stream, deg, N);
    hipLaunchKernelGGL(k_count_deg, gridE, blk256, 0, stream, ei_i, deg, E);
    hipLaunchKernelGGL(k_scan_local, dim3(nScanB), dim3(SCB), 0, stream, deg, offs, btot, dinv, N);
    hipLaunchKernelGGL(k_scan_tots, dim3(1), dim3(64), 0, stream, btot, bpre, nScanB, offs + N);
    hipLaunchKernelGGL(k_scan_apply, dim3(256), blk256, 0, stream, offs, bpre, cursor, N);
    hipLaunchKernelGGL(k_fill_csr, gridE, blk256, 0, stream, ei_j, ei_i, cursor, csr, E);
    hipLaunchKernelGGL(k_conv_w4, gridW, blk256, 0, stream,
                       gcn1_W, hw1_W, ghw1_W, ghw2_W, wb0, wb1, wb2, wb3);

    // 3. hb = bf16(x0 @ gcn1_W.T) -> W1
    hipLaunchKernelGGL(k_gemm_fused, gridGemm, blk256, 0, stream,
                       W0, wb0, W1,
                       (const float*)nullptr, (const u16*)nullptr, (const float*)nullptr,
                       (const u16*)nullptr, (float*)nullptr, (long)0, (u16*)nullptr, N);

    // 4. gcnb -> W2
    hipLaunchKernelGGL(k_gcn_gather_w, gridNodeW, blk256, 0, stream, W1, dinv, offs, csr, W2, N);

    // 5. x2b = hw(x0b, gcnb) fused: pre = x0b@hw1_W.T -> mirror W3
    hipLaunchKernelGGL(k_gemm_fused, gridGemm, blk256, 0, stream,
                       W0, wb1, (u16*)nullptr,
                       hw1_b, W2, (const float*)nullptr, W0,
                       (float*)nullptr, (long)0, W3, N);

    // 6. dots for GAT1 from x2b
    hipLaunchKernelGGL(k_dual_dot_b, gridRows, blk256, 0, stream, W3, gat1_ai, gat1_aj, sbi, sbj, N);

    // 7. GAT1 gather on x2b -> g1b (W1)
    hipLaunchKernelGGL(k_gat_gather_w, gridNodeW, blk256, 0, stream, W3, sbi, sbj, offs, csr,
                       W1, (float*)nullptr, (long)0, 0, N);

    // 8. x3b = hw(x2b, g1b) fused: pre = x2b@ghw1_W.T -> mirror W2
    hipLaunchKernelGGL(k_gemm_fused, gridGemm, blk256, 0, stream,
                       W3, wb2, (u16*)nullptr,
                       ghw1_b, W1, (const float*)nullptr, W3,
                       (float*)nullptr, (long)0, W2, N);

    // 9. dots for GAT2 from x3b
    hipLaunchKernelGGL(k_dual_dot_b, gridRows, blk256, 0, stream, W2, gat2_ai, gat2_aj, sbi, sbj, N);

    // 10. GAT2 gather on x3b -> G2F (fp32, contiguous stride H)
    hipLaunchKernelGGL(k_gat_gather_w, gridNodeW, blk256, 0, stream, W2, sbi, sbj, offs, csr,
                       (u16*)nullptr, G2F, (long)H, 0, N);

    // 11. xe = hw(x2b, G2F) fused: pre = x2b@ghw2_W.T -> d_out[:,0:300] fp32 + mirror xeb (W2)
    hipLaunchKernelGGL(k_gemm_fused, gridGemm, blk256, 0, stream,
                       W3, wb3, (u16*)nullptr,
                       ghw2_b, (const u16*)nullptr, G2F, W3,
                       out, (long)(2 * H), W2, N);

    // 12. dots for final GAT from xeb
    hipLaunchKernelGGL(k_dual_dot_b, gridRows, blk256, 0, stream, W2, gat_ai, gat_aj, sbi, sbj, N);

    // 13. final GAT gather on xeb -> d_out[:,300:600]
    hipLaunchKernelGGL(k_gat_gather_w, gridNodeW, blk256, 0, stream, W2, sbi, sbj, offs, csr,
                       (u16*)nullptr, out, (long)(2 * H), H, N);
}

// Round 16
// 661.763 us; speedup vs baseline: 1.0675x; 1.0060x over previous
//
#include <hip/hip_runtime.h>
#include <hip/hip_bf16.h>
#include <math.h>

#define H 300
#define WAVE 64
#define STRB 320   // padded bf16 row stride (640 B; 80 chunks of 8 B)
#define SCB 1024

typedef short bf16x8 __attribute__((ext_vector_type(8)));
typedef unsigned short u16;
typedef u16 u16x8 __attribute__((ext_vector_type(8)));
typedef u16 u16x4 __attribute__((ext_vector_type(4)));
typedef float f32x4 __attribute__((ext_vector_type(4)));

__device__ inline unsigned short f2b(float f) {
    union { float f; unsigned int u; } x; x.f = f;
    unsigned int r = x.u + 0x7FFF + ((x.u >> 16) & 1);
    return (unsigned short)(r >> 16);
}
__device__ inline float b2f(u16 h) {
    union { float f; unsigned int u; } x; x.u = ((unsigned int)h) << 16;
    return x.f;
}

// ---------------------------------------------------------------------------
// l2 normalize rows: one wave per row; bf16 padded output only
// ---------------------------------------------------------------------------
__global__ void k_l2norm(const float* __restrict__ x, u16* __restrict__ outb, int n) {
    int wave = blockIdx.x * (blockDim.x / WAVE) + (threadIdx.x >> 6);
    int lane = threadIdx.x & 63;
    if (wave >= n) return;
    const float* row = x + (long)wave * H;
    float s = 0.f;
    for (int j = lane; j < H; j += WAVE) { float v = row[j]; s += v * v; }
    for (int o = 32; o > 0; o >>= 1) s += __shfl_xor(s, o);
    float sc = 1.0f / fmaxf(sqrtf(s), 1e-12f);
    u16* brow = outb + (long)wave * STRB;
    for (int j = lane; j < H; j += WAVE) brow[j] = f2b(row[j] * sc);
    for (int j = H + lane; j < STRB; j += WAVE) brow[j] = 0;
}

__global__ void k_zero_int(int* p, int n) {
    int i = blockIdx.x * blockDim.x + threadIdx.x;
    int stride = gridDim.x * blockDim.x;
    for (; i < n; i += stride) p[i] = 0;
}

__global__ void k_count_deg(const int* __restrict__ ei_i, int* __restrict__ deg, int E) {
    int i = blockIdx.x * blockDim.x + threadIdx.x;
    int stride = gridDim.x * blockDim.x;
    for (; i < E; i += stride) atomicAdd(&deg[ei_i[i]], 1);
}

// ---------------------------------------------------------------------------
// parallel exclusive scan of deg -> offs(+cursor), offs[n]=total; dinv fused
// ---------------------------------------------------------------------------
__global__ void k_scan_local(const int* __restrict__ deg, int* __restrict__ offs,
                             int* __restrict__ btot, float* __restrict__ dinv, int n) {
    __shared__ int sh[SCB];
    int base = blockIdx.x * SCB;
    int tid = threadIdx.x;
    int v = (base + tid < n) ? deg[base + tid] : 0;
    if (base + tid < n) dinv[base + tid] = (v > 0) ? 1.0f / sqrtf((float)v) : 0.0f;
    sh[tid] = v;
    __syncthreads();
    for (int off = 1; off < SCB; off <<= 1) {
        int add = (tid >= off) ? sh[tid - off] : 0;
        __syncthreads();
        sh[tid] += add;
        __syncthreads();
    }
    if (base + tid < n) offs[base + tid] = sh[tid] - v;
    if (tid == SCB - 1) btot[blockIdx.x] = sh[tid];
}

__global__ void k_scan_tots(const int* __restrict__ btot, int* __restrict__ bpre,
                            int nb, int* __restrict__ total_out) {
    int l = threadIdx.x;   // single wave of 64; nb <= 64
    int v = (l < nb) ? btot[l] : 0;
    int own = v;
    for (int o = 1; o < 64; o <<= 1) {
        int u = __shfl_up(v, o);
        if (l >= o) v += u;
    }
    if (l < nb) bpre[l] = v - own;
    if (l == 63) total_out[0] = v;
}

__global__ void k_scan_apply(int* __restrict__ offs, const int* __restrict__ bpre,
                             int* __restrict__ cursor, int n) {
    int i = blockIdx.x * blockDim.x + threadIdx.x;
    int stride = gridDim.x * blockDim.x;
    for (; i < n; i += stride) {
        int o = offs[i] + bpre[i / SCB];
        offs[i] = o;
        cursor[i] = o;
    }
}

__global__ void k_fill_csr(const int* __restrict__ ei_j, const int* __restrict__ ei_i,
                           int* __restrict__ cursor, int* __restrict__ csr_src, int E) {
    int i = blockIdx.x * blockDim.x + threadIdx.x;
    int stride = gridDim.x * blockDim.x;
    for (; i < E; i += stride) {
        int dst = ei_i[i];
        int pos = atomicAdd(&cursor[dst], 1);
        csr_src[pos] = ei_j[i];
    }
}

// ---------------------------------------------------------------------------
// 4x W fp32 [300][300] -> padded bf16 [320][320], pads zero. One launch.
// ---------------------------------------------------------------------------
__global__ void k_conv_w4(const float* __restrict__ W0f, const float* __restrict__ W1f,
                          const float* __restrict__ W2f, const float* __restrict__ W3f,
                          u16* __restrict__ Wb0, u16* __restrict__ Wb1,
                          u16* __restrict__ Wb2, u16* __restrict__ Wb3) {
    int which = blockIdx.x & 3;
    const float* W = (which == 0) ? W0f : (which == 1) ? W1f : (which == 2) ? W2f : W3f;
    u16* Wb = (which == 0) ? Wb0 : (which == 1) ? Wb1 : (which == 2) ? Wb2 : Wb3;
    int idx = (blockIdx.x >> 2) * blockDim.x + threadIdx.x;
    int stride = (gridDim.x >> 2) * blockDim.x;
    for (; idx < STRB * STRB; idx += stride) {
        int r = idx / STRB, c = idx - r * STRB;
        Wb[idx] = (r < H && c < H) ? f2b(W[r * H + c]) : 0;
    }
}

// ---------------------------------------------------------------------------
// MFMA NT GEMM, BM=128 x BN=64, 1-D grid bn-fast + bijective XCD swizzle.
// Epilogue: acc -> bf16 LDS tile [128][70] -> row-major vectorized I/O.
// ---------------------------------------------------------------------------
#define BM 128
#define BN 64
#define BK 32
#define LDP 40
#define STP 70   // epilogue staging stride (u16)
#define NXCD 8

__global__ __launch_bounds__(256) void k_gemm_fused(
        const u16* __restrict__ Xb,
        const u16* __restrict__ Wb,
        u16* __restrict__ outb,
        const float* __restrict__ hwbias,
        const u16* __restrict__ xnewb, const float* __restrict__ xnewf,
        const u16* __restrict__ xold,
        float* __restrict__ outf, long ostride,
        u16* __restrict__ mirror,
        int n_rows) {
    __shared__ __align__(16) char smem[BM * STP * 2];   // 17920 B
    short* As = (short*)smem;                           // [BM][LDP]
    short* Bs = (short*)(smem + BM * LDP * 2);          // [BN][LDP]
    u16*   St = (u16*)smem;                             // [BM][STP] (epilogue)
    const int tid = threadIdx.x;

    const int nwg = gridDim.x;
    const int q = nwg / NXCD, r = nwg % NXCD;
    const int xcd = blockIdx.x % NXCD, idx = blockIdx.x / NXCD;
    const int wgid = (xcd < r ? xcd * (q + 1) : r * (q + 1) + (xcd - r) * q) + idx;
    const int bm = (wgid / 5) * BM;
    const int bn = (wgid % 5) * BN;

    const int lane = tid & 63;
    const int wid = tid >> 6;
    const int wr = wid >> 1;
    const int wc = wid & 1;
    const int lrow = lane & 15;
    const int kgrp = lane >> 4;

    f32x4 acc[4][2];
    #pragma unroll
    for (int m = 0; m < 4; m++)
        #pragma unroll
        for (int n = 0; n < 2; n++) acc[m][n] = (f32x4){0.f, 0.f, 0.f, 0.f};

    for (int k0 = 0; k0 < STRB; k0 += BK) {
        #pragma unroll
        for (int i = 0; i < 2; ++i) {
            int qq = tid + i * 256;
            int rr = qq >> 2, c = (qq & 3) << 3;
            int gr = bm + rr;
            u16x8 v = {0, 0, 0, 0, 0, 0, 0, 0};
            if (gr < n_rows) v = *(const u16x8*)&Xb[(long)gr * STRB + k0 + c];
            *(u16x8*)&As[rr * LDP + c] = v;
        }
        {
            int rr = tid >> 2, c = (tid & 3) << 3;
            u16x8 v = *(const u16x8*)&Wb[(long)(bn + rr) * STRB + k0 + c];
            *(u16x8*)&Bs[rr * LDP + c] = v;
        }
        __syncthreads();

        bf16x8 af[4], bfr[2];
        #pragma unroll
        for (int m = 0; m < 4; m++) {
            int row = wr * 64 + m * 16 + lrow;
            af[m] = *(const bf16x8*)&As[row * LDP + kgrp * 8];
        }
        #pragma unroll
        for (int n = 0; n < 2; n++) {
            int col = wc * 32 + n * 16 + lrow;
            bfr[n] = *(const bf16x8*)&Bs[col * LDP + kgrp * 8];
        }
        #pragma unroll
        for (int m = 0; m < 4; m++)
            #pragma unroll
            for (int n = 0; n < 2; n++)
                acc[m][n] = __builtin_amdgcn_mfma_f32_16x16x32_bf16(af[m], bfr[n], acc[m][n], 0, 0, 0);
        __syncthreads();
    }

    // stage acc (bf16) into LDS tile [128][STP]
    #pragma unroll
    for (int m = 0; m < 4; m++)
        #pragma unroll
        for (int n = 0; n < 2; n++) {
            int lc = wc * 32 + n * 16 + lrow;
            #pragma unroll
            for (int rr = 0; rr < 4; rr++) {
                int row = wr * 64 + m * 16 + kgrp * 4 + rr;
                St[row * STP + lc] = f2b(acc[m][n][rr]);
            }
        }
    __syncthreads();

    // vectorized epilogue: 8 threads/row, 4 passes of 32 rows
    #pragma unroll
    for (int p = 0; p < 4; p++) {
        int row = p * 32 + (tid >> 3);
        int gr = bm + row;
        if (gr >= n_rows) continue;
        int lc0 = (tid & 7) * 8;
        int gc0 = bn + lc0;
        u16x8 pv = *(const u16x8*)&St[row * STP + lc0];
        if (outb) {
            u16x8 o;
            #pragma unroll
            for (int j = 0; j < 8; j++) o[j] = (gc0 + j < H) ? pv[j] : (u16)0;
            *(u16x8*)&outb[(long)gr * STRB + gc0] = o;
        } else {
            u16x8 xov = *(const u16x8*)&xold[(long)gr * STRB + gc0];
            float xn[8];
            if (xnewb) {
                u16x8 xnv = *(const u16x8*)&xnewb[(long)gr * STRB + gc0];
                #pragma unroll
                for (int j = 0; j < 8; j++) xn[j] = b2f(xnv[j]);
            } else {
                f32x4 a = *(const f32x4*)&xnewf[(long)gr * H + gc0];
                f32x4 b = *(const f32x4*)&xnewf[(long)gr * H + gc0 + 4];
                xn[0] = a[0]; xn[1] = a[1]; xn[2] = a[2]; xn[3] = a[3];
                xn[4] = b[0]; xn[5] = b[1]; xn[6] = b[2]; xn[7] = b[3];
            }
            float val[8];
            #pragma unroll
            for (int j = 0; j < 8; j++) {
                int gcj = gc0 + j;
                if (gcj < H) {
                    float pre = b2f(pv[j]) + hwbias[gcj];
                    float g = 1.0f / (1.0f + __expf(-pre));
                    val[j] = g * xn[j] + (1.0f - g) * b2f(xov[j]);
                } else val[j] = 0.f;
            }
            if (outf) {
                if (gc0 < H)
                    *(f32x4*)&outf[(long)gr * ostride + gc0] = (f32x4){val[0], val[1], val[2], val[3]};
                if (gc0 + 4 < H)
                    *(f32x4*)&outf[(long)gr * ostride + gc0 + 4] = (f32x4){val[4], val[5], val[6], val[7]};
            }
            if (mirror) {
                u16x8 mv;
                #pragma unroll
                for (int j = 0; j < 8; j++) mv[j] = f2b(val[j]);
                *(u16x8*)&mirror[(long)gr * STRB + gc0] = mv;
            }
        }
    }
}

// ---------------------------------------------------------------------------
// GCN gather, wave-per-node, 4 edges x 16 lanes x 5 u16x4 chunks (full lanes).
// slot = lane>>4 picks edge; slot-reduce via shfl_xor(16,32) at the end.
// ---------------------------------------------------------------------------
__global__ __launch_bounds__(256) void k_gcn_gather_w(const u16* __restrict__ xb,
                                                      const float* __restrict__ dinv,
                                                      const int* __restrict__ offs,
                                                      const int* __restrict__ csr,
                                                      u16* __restrict__ outb, int n) {
    int node = blockIdx.x * 4 + (threadIdx.x >> 6);
    int lane = threadIdx.x & 63;
    if (node >= n) return;
    int start = offs[node], end = offs[node + 1];
    int slot = lane >> 4;            // 0..3 edge slot
    int ce = (lane & 15) * 20;       // element base: 5 u16x4 chunks = 20 elems
    float acc[5][4];
    #pragma unroll
    for (int k = 0; k < 5; k++)
        #pragma unroll
        for (int j = 0; j < 4; j++) acc[k][j] = 0.f;
    float di = dinv[node];
    const u16* basep = xb + ce;
    for (int tb = start; tb < end; tb += 64) {
        int p = tb + lane;
        int src = 0; float w = 0.f;
        if (p < end) {
            src = csr[p];
            w = di * dinv[src];
        }
        int cnt = min(64, end - tb);
        for (int qb = 0; qb < cnt; qb += 4) {
            int myq = qb + slot;
            float wq = __shfl(w, myq);
            int sq = __shfl(src, myq);
            if (myq < cnt) {
                const u16* row = basep + (long)sq * STRB;
                u16x4 v0 = *(const u16x4*)(row);
                u16x4 v1 = *(const u16x4*)(row + 4);
                u16x4 v2 = *(const u16x4*)(row + 8);
                u16x4 v3 = *(const u16x4*)(row + 12);
                u16x4 v4 = *(const u16x4*)(row + 16);
                #pragma unroll
                for (int j = 0; j < 4; j++) acc[0][j] += wq * b2f(v0[j]);
                #pragma unroll
                for (int j = 0; j < 4; j++) acc[1][j] += wq * b2f(v1[j]);
                #pragma unroll
                for (int j = 0; j < 4; j++) acc[2][j] += wq * b2f(v2[j]);
                #pragma unroll
                for (int j = 0; j < 4; j++) acc[3][j] += wq * b2f(v3[j]);
                #pragma unroll
                for (int j = 0; j < 4; j++) acc[4][j] += wq * b2f(v4[j]);
            }
        }
    }
    // reduce across the 4 slots (lanes l, l^16, l^32, l^48 share chunk group)
    #pragma unroll
    for (int k = 0; k < 5; k++)
        #pragma unroll
        for (int j = 0; j < 4; j++) {
            float v = acc[k][j];
            v += __shfl_xor(v, 16);
            v += __shfl_xor(v, 32);
            acc[k][j] = v;
        }
    if (slot == 0) {
        u16* orow = outb + (long)node * STRB + ce;
        #pragma unroll
        for (int k = 0; k < 5; k++) {
            u16x4 o;
            #pragma unroll
            for (int j = 0; j < 4; j++) o[j] = f2b(fmaxf(acc[k][j], 0.f));
            *(u16x4*)(orow + k * 4) = o;
        }
    }
}

// ---------------------------------------------------------------------------
// dual dot from bf16 mirror: one wave per row
// ---------------------------------------------------------------------------
__global__ void k_dual_dot_b(const u16* __restrict__ xb,
                             const float* __restrict__ ai, const float* __restrict__ aj,
                             float* __restrict__ s_i, float* __restrict__ s_j, int n) {
    int wave = blockIdx.x * (blockDim.x / WAVE) + (threadIdx.x >> 6);
    int lane = threadIdx.x & 63;
    if (wave >= n) return;
    const u16* row = xb + (long)wave * STRB;
    float d0 = 0.f, d1 = 0.f;
    {
        u16x4 v = *(const u16x4*)&row[lane * 4];
        float4 a4 = *(const float4*)&ai[lane * 4];
        float4 j4 = *(const float4*)&aj[lane * 4];
        float x0 = b2f(v[0]), x1 = b2f(v[1]), x2 = b2f(v[2]), x3 = b2f(v[3]);
        d0 = x0 * a4.x + x1 * a4.y + x2 * a4.z + x3 * a4.w;
        d1 = x0 * j4.x + x1 * j4.y + x2 * j4.z + x3 * j4.w;
    }
    if (lane < 11) {
        u16x4 v = *(const u16x4*)&row[256 + lane * 4];
        float4 a4 = *(const float4*)&ai[256 + lane * 4];
        float4 j4 = *(const float4*)&aj[256 + lane * 4];
        float x0 = b2f(v[0]), x1 = b2f(v[1]), x2 = b2f(v[2]), x3 = b2f(v[3]);
        d0 += x0 * a4.x + x1 * a4.y + x2 * a4.z + x3 * a4.w;
        d1 += x0 * j4.x + x1 * j4.y + x2 * j4.z + x3 * j4.w;
    }
    for (int o = 32; o > 0; o >>= 1) { d0 += __shfl_down(d0, o); d1 += __shfl_down(d1, o); }
    if (lane == 0) { s_i[wave] = d0; s_j[wave] = d1; }
}

// ---------------------------------------------------------------------------
// GAT gather, wave-per-node, fused softmax + 4x16x5 full-lane edge pipeline.
// ---------------------------------------------------------------------------
__global__ __launch_bounds__(256) void k_gat_gather_w(const u16* __restrict__ xb,
                                                      const float* __restrict__ s_i_arr,
                                                      const float* __restrict__ s_j_arr,
                                                      const int* __restrict__ offs,
                                                      const int* __restrict__ csr,
                                                      u16* __restrict__ outb16,
                                                      float* __restrict__ outf, long out_stride,
                                                      int out_off, int n) {
    int node = blockIdx.x * 4 + (threadIdx.x >> 6);
    int lane = threadIdx.x & 63;
    if (node >= n) return;
    int start = offs[node], end = offs[node + 1];
    int deg = end - start;
    int slot = lane >> 4;
    int ce = (lane & 15) * 20;
    float acc[5][4];
    #pragma unroll
    for (int k = 0; k < 5; k++)
        #pragma unroll
        for (int j = 0; j < 4; j++) acc[k][j] = 0.f;

    if (deg > 0) {
        float si = s_i_arr[node];
        float m_t = -1e30f, s_t = 0.f;
        for (int p = start + lane; p < end; p += 64) {
            float sc = si + s_j_arr[csr[p]];
            sc = (sc >= 0.f) ? sc : 0.01f * sc;
            if (sc > m_t) { s_t = s_t * __expf(m_t - sc) + 1.0f; m_t = sc; }
            else s_t += __expf(sc - m_t);
        }
        for (int o = 32; o > 0; o >>= 1) {
            float m2 = __shfl_xor(m_t, o), s2 = __shfl_xor(s_t, o);
            float mm = fmaxf(m_t, m2);
            s_t = s_t * __expf(m_t - mm) + s2 * __expf(m2 - mm);
            m_t = mm;
        }
        float m = m_t;
        float inv = 1.0f / (s_t + 1e-16f);
        const u16* basep = xb + ce;
        for (int tb = start; tb < end; tb += 64) {
            int p = tb + lane;
            int src = 0; float w = 0.f;
            if (p < end) {
                src = csr[p];
                float sc = si + s_j_arr[src];
                sc = (sc >= 0.f) ? sc : 0.01f * sc;
                w = __expf(sc - m) * inv;
            }
            int cnt = min(64, end - tb);
            for (int qb = 0; qb < cnt; qb += 4) {
                int myq = qb + slot;
                float wq = __shfl(w, myq);
                int sq = __shfl(src, myq);
                if (myq < cnt) {
                    const u16* row = basep + (long)sq * STRB;
                    u16x4 v0 = *(const u16x4*)(row);
                    u16x4 v1 = *(const u16x4*)(row + 4);
                    u16x4 v2 = *(const u16x4*)(row + 8);
                    u16x4 v3 = *(const u16x4*)(row + 12);
                    u16x4 v4 = *(const u16x4*)(row + 16);
                    #pragma unroll
                    for (int j = 0; j < 4; j++) acc[0][j] += wq * b2f(v0[j]);
                    #pragma unroll
                    for (int j = 0; j < 4; j++) acc[1][j] += wq * b2f(v1[j]);
                    #pragma unroll
                    for (int j = 0; j < 4; j++) acc[2][j] += wq * b2f(v2[j]);
                    #pragma unroll
                    for (int j = 0; j < 4; j++) acc[3][j] += wq * b2f(v3[j]);
                    #pragma unroll
                    for (int j = 0; j < 4; j++) acc[4][j] += wq * b2f(v4[j]);
                }
            }
        }
    }
    // slot-reduce
    #pragma unroll
    for (int k = 0; k < 5; k++)
        #pragma unroll
        for (int j = 0; j < 4; j++) {
            float v = acc[k][j];
            v += __shfl_xor(v, 16);
            v += __shfl_xor(v, 32);
            acc[k][j] = v;
        }
    if (slot == 0) {
        if (outb16) {
            u16* orow = outb16 + (long)node * STRB + ce;
            #pragma unroll
            for (int k = 0; k < 5; k++) {
                u16x4 o;
                #pragma unroll
                for (int j = 0; j < 4; j++) o[j] = f2b(fmaxf(acc[k][j], 0.f));
                *(u16x4*)(orow + k * 4) = o;
            }
        } else {
            float* orow = outf + (long)node * out_stride + out_off;
            #pragma unroll
            for (int k = 0; k < 5; k++) {
                int c0 = ce + k * 4;
                if (c0 < H) {
                    f32x4 o = (f32x4){fmaxf(acc[k][0], 0.f), fmaxf(acc[k][1], 0.f),
                                      fmaxf(acc[k][2], 0.f), fmaxf(acc[k][3], 0.f)};
                    *(f32x4*)(orow + c0) = o;
                }
            }
        }
    }
}

// ---------------------------------------------------------------------------
// launch
// ---------------------------------------------------------------------------
extern "C" void kernel_launch(void* const* d_in, const int* in_sizes, int n_in,
                              void* d_out, int out_size, void* d_ws, size_t ws_size,
                              hipStream_t stream) {
    const float* x_e     = (const float*)d_in[0];
    const int*   ei_all  = (const int*)d_in[3];
    const float* gcn1_W  = (const float*)d_in[5];
    const float* hw1_W   = (const float*)d_in[6];
    const float* hw1_b   = (const float*)d_in[7];
    const float* gat1_ai = (const float*)d_in[8];
    const float* gat1_aj = (const float*)d_in[9];
    const float* ghw1_W  = (const float*)d_in[10];
    const float* ghw1_b  = (const float*)d_in[11];
    const float* gat2_ai = (const float*)d_in[12];
    const float* gat2_aj = (const float*)d_in[13];
    const float* ghw2_W  = (const float*)d_in[14];
    const float* ghw2_b  = (const float*)d_in[15];
    const float* gat_ai  = (const float*)d_in[16];
    const float* gat_aj  = (const float*)d_in[17];

    const int N = in_sizes[0] / H;
    const int E = in_sizes[3] / 2;
    const int* ei_j = ei_all;
    const int* ei_i = ei_all + E;

    float* out = (float*)d_out;

    size_t NSB = (size_t)N * STRB;
    u16*   W0   = (u16*)d_ws;
    u16*   W1   = W0 + NSB;
    u16*   W2   = W1 + NSB;
    u16*   W3   = W2 + NSB;
    float* G2F  = (float*)d_ws;              // spans [0, 60MB) ⊂ W0+W1 (64MB)
    float* sbi  = (float*)(W3 + NSB);
    float* sbj  = sbi + N;
    float* dinv = sbj + N;
    int*   deg  = (int*)(dinv + N);
    int*   offs = deg + N;                   // N+1
    int*   cursor = offs + (N + 1);
    int*   csr  = cursor + N;                // E ints
    int*   btot = csr + E;                   // 64
    int*   bpre = btot + 64;                 // 64
    u16*   wb0  = (u16*)(bpre + 64);         // 4 x 320x320 bf16 weights
    u16*   wb1  = wb0 + STRB * STRB;
    u16*   wb2  = wb1 + STRB * STRB;
    u16*   wb3  = wb2 + STRB * STRB;

    dim3 blk256(256);
    int rowsPerBlock = 256 / WAVE;
    dim3 gridRows((N + rowsPerBlock - 1) / rowsPerBlock);
    dim3 gridNodeW((N + 3) / 4);
    dim3 gridE(2048);
    dim3 gridW(400);
    dim3 gridGemm(((N + BM - 1) / BM) * 5);
    int nScanB = (N + SCB - 1) / SCB;

    // 1. x0b = bf16(l2_normalize(x_e)) -> W0
    hipLaunchKernelGGL(k_l2norm, gridRows, blk256, 0, stream, x_e, W0, N);

    // 2. CSR build + weight conversion
    hipLaunchKernelGGL(k_zero_int, dim3(256), blk256, 0, stream, deg, N);
    hipLaunchKernelGGL(k_count_deg, gridE, blk256, 0, stream, ei_i, deg, E);
    hipLaunchKernelGGL(k_scan_local, dim3(nScanB), dim3(SCB), 0, stream, deg, offs, btot, dinv, N);
    hipLaunchKernelGGL(k_scan_tots, dim3(1), dim3(64), 0, stream, btot, bpre, nScanB, offs + N);
    hipLaunchKernelGGL(k_scan_apply, dim3(256), blk256, 0, stream, offs, bpre, cursor, N);
    hipLaunchKernelGGL(k_fill_csr, gridE, blk256, 0, stream, ei_j, ei_i, cursor, csr, E);
    hipLaunchKernelGGL(k_conv_w4, gridW, blk256, 0, stream,
                       gcn1_W, hw1_W, ghw1_W, ghw2_W, wb0, wb1, wb2, wb3);

    // 3. hb = bf16(x0 @ gcn1_W.T) -> W1
    hipLaunchKernelGGL(k_gemm_fused, gridGemm, blk256, 0, stream,
                       W0, wb0, W1,
                       (const float*)nullptr, (const u16*)nullptr, (const float*)nullptr,
                       (const u16*)nullptr, (float*)nullptr, (long)0, (u16*)nullptr, N);

    // 4. gcnb -> W2
    hipLaunchKernelGGL(k_gcn_gather_w, gridNodeW, blk256, 0, stream, W1, dinv, offs, csr, W2, N);

    // 5. x2b = hw(x0b, gcnb) fused: pre = x0b@hw1_W.T -> mirror W3
    hipLaunchKernelGGL(k_gemm_fused, gridGemm, blk256, 0, stream,
                       W0, wb1, (u16*)nullptr,
                       hw1_b, W2, (const float*)nullptr, W0,
                       (float*)nullptr, (long)0, W3, N);

    // 6. dots for GAT1 from x2b
    hipLaunchKernelGGL(k_dual_dot_b, gridRows, blk256, 0, stream, W3, gat1_ai, gat1_aj, sbi, sbj, N);

    // 7. GAT1 gather on x2b -> g1b (W1)
    hipLaunchKernelGGL(k_gat_gather_w, gridNodeW, blk256, 0, stream, W3, sbi, sbj, offs, csr,
                       W1, (float*)nullptr, (long)0, 0, N);

    // 8. x3b = hw(x2b, g1b) fused: pre = x2b@ghw1_W.T -> mirror W2
    hipLaunchKernelGGL(k_gemm_fused, gridGemm, blk256, 0, stream,
                       W3, wb2, (u16*)nullptr,
                       ghw1_b, W1, (const float*)nullptr, W3,
                       (float*)nullptr, (long)0, W2, N);

    // 9. dots for GAT2 from x3b
    hipLaunchKernelGGL(k_dual_dot_b, gridRows, blk256, 0, stream, W2, gat2_ai, gat2_aj, sbi, sbj, N);

    // 10. GAT2 gather on x3b -> G2F (fp32, contiguous stride H)
    hipLaunchKernelGGL(k_gat_gather_w, gridNodeW, blk256, 0, stream, W2, sbi, sbj, offs, csr,
                       (u16*)nullptr, G2F, (long)H, 0, N);

    // 11. xe = hw(x2b, G2F) fused: pre = x2b@ghw2_W.T -> d_out[:,0:300] fp32 + mirror xeb (W2)
    hipLaunchKernelGGL(k_gemm_fused, gridGemm, blk256, 0, stream,
                       W3, wb3, (u16*)nullptr,
                       ghw2_b, (const u16*)nullptr, G2F, W3,
                       out, (long)(2 * H), W2, N);

    // 12. dots for final GAT from xeb
    hipLaunchKernelGGL(k_dual_dot_b, gridRows, blk256, 0, stream, W2, gat_ai, gat_aj, sbi, sbj, N);

    // 13. final GAT gather on xeb -> d_out[:,300:600]
    hipLaunchKernelGGL(k_gat_gather_w, gridNodeW, blk256, 0, stream, W2, sbi, sbj, offs, csr,
                       (u16*)nullptr, out, (long)(2 * H), H, N);
}